// Round 3
// baseline (253.682 us; speedup 1.0000x reference)
//
#include <hip/hip_runtime.h>

// 20-qubit statevector, 8 layers {Ry x20, CZ chain, Rzz chain}, out = |psi|^2.
// R3: single persistent mega-kernel. 8 sweeps (init + 3x{low,hi} + last-low)
// separated by 7 device-scope grid barriers (256 blocks == 256 CUs, 1 block/CU
// co-resident; monotonic-counter barrier w/ __threadfence + device atomics).
// Per sweep: 4 amps/thread in registers; rotations on reg bits (free) and
// lane bits (DPP, VALU pipe); wave bits moved by TWO XOR-swizzled LDS
// transpose passes. Each sweep's tail builds the NEXT sweep's diagonal
// tables (Plo/Phh are layout-independent), hiding the sincos under the
// store/barrier window.
// Layouts (tile index n[11:0], thread t[9:0], amp j[1:0]):
//  L0: reg={n1,n0} lanes={n7..n2} wave={n11..n8}   (global-coalesced order)
//  Q : reg={n7,n6} lanes={n5,n4 parked | n11..n8}  wave={n3..n0}
// DPP semantics: row_shr:N = from lane i-N, row_shl:N = from lane i+N.

#define QN 20
#define NBLK 256

__device__ __forceinline__ float2 cmulf(float2 a, float2 b) {
    return make_float2(a.x * b.x - a.y * b.y, a.x * b.y + a.y * b.x);
}

// ---- rotation on register bits: w = (cos, sin) -----------------------------
__device__ __forceinline__ void rot2c(float2& x0, float2& x1, float2 w) {
    float2 t0 = make_float2(w.x * x0.x - w.y * x1.x, w.x * x0.y - w.y * x1.y);
    float2 t1 = make_float2(w.y * x0.x + w.x * x1.x, w.y * x0.y + w.x * x1.y);
    x0 = t0; x1 = t1;
}
__device__ __forceinline__ void rot4c(float2& a0, float2& a1, float2& a2, float2& a3,
                                      float2 wa, float2 wb) {
    rot2c(a0, a1, wa); rot2c(a2, a3, wa);
    rot2c(a0, a2, wb); rot2c(a1, a3, wb);
}

// ---- DPP cross-lane partner fetch (xor distance X in {1,2,4,8}) ------------
template<int X>
__device__ __forceinline__ float2 xpart(float2 v, int t) {
    int sx = __float_as_int(v.x), sy = __float_as_int(v.y);
    if constexpr (X == 4) {
        // row_shr:4 (0x114): lane i <- i-4 (valid for t&4=1); row_shl:4
        // (0x104): lane i <- i+4 (valid for t&4=0); select by side.
        int ax = __builtin_amdgcn_update_dpp(sx, sx, 0x114, 0xF, 0xF, false);
        int ay = __builtin_amdgcn_update_dpp(sy, sy, 0x114, 0xF, 0xF, false);
        int bx = __builtin_amdgcn_update_dpp(sx, sx, 0x104, 0xF, 0xF, false);
        int by = __builtin_amdgcn_update_dpp(sy, sy, 0x104, 0xF, 0xF, false);
        bool hi = (t & 4) != 0;
        return make_float2(__int_as_float(hi ? ax : bx), __int_as_float(hi ? ay : by));
    } else {
        // xor1: quad_perm[1,0,3,2]=0xB1; xor2: quad_perm[2,3,0,1]=0x4E;
        // xor8: row_ror:8=0x128 ((i+8)%16 == i^8 within a 16-row)
        constexpr int ctrl = (X == 1) ? 0xB1 : (X == 2) ? 0x4E : 0x128;
        return make_float2(
            __int_as_float(__builtin_amdgcn_update_dpp(sx, sx, ctrl, 0xF, 0xF, false)),
            __int_as_float(__builtin_amdgcn_update_dpp(sy, sy, ctrl, 0xF, 0xF, false)));
    }
}

// Ry on a lane bit: own' = c*own + (side? +s : -s)*partner
template<int X>
__device__ __forceinline__ void lrot4(float2& a0, float2& a1, float2& a2, float2& a3,
                                      float2 w, int t) {
    float ss = (t & X) ? w.y : -w.y;
    float2 p0 = xpart<X>(a0, t), p1 = xpart<X>(a1, t),
           p2 = xpart<X>(a2, t), p3 = xpart<X>(a3, t);
    a0 = make_float2(fmaf(ss, p0.x, w.x * a0.x), fmaf(ss, p0.y, w.x * a0.y));
    a1 = make_float2(fmaf(ss, p1.x, w.x * a1.x), fmaf(ss, p1.y, w.x * a1.y));
    a2 = make_float2(fmaf(ss, p2.x, w.x * a2.x), fmaf(ss, p2.y, w.x * a2.y));
    a3 = make_float2(fmaf(ss, p3.x, w.x * a3.x), fmaf(ss, p3.y, w.x * a3.y));
}

// ---- diagonal (CZ chain + Rzz chain) phase ---------------------------------
__device__ __forceinline__ float2 dphase(int x, const float2* Plo, const float2* Phh) {
    int y = (x ^ (x >> 1)) & 0x7FFFF;
    float2 p = cmulf(Plo[y & 1023], Phh[y >> 10]);
    int sgn = (__popc(x & (x >> 1) & 0x7FFFF) & 1) << 31;
    p.x = __int_as_float(__float_as_int(p.x) ^ sgn);
    p.y = __int_as_float(__float_as_int(p.y) ^ sgn);
    return p;
}

__device__ __forceinline__ void build_D(float2* Plo, float2* Phh,
                                        const float* __restrict__ ph, int t) {
    float pw[19];
    #pragma unroll
    for (int j = 0; j < 19; ++j) pw[j] = ph[18 - j];   // uniform loads
    float S = 0.f;
    #pragma unroll
    for (int j = 0; j < 19; ++j) S += pw[j];
    float ang = 0.f;
    #pragma unroll
    for (int j = 0; j < 10; ++j) if ((t >> j) & 1) ang += pw[j];
    Plo[t] = make_float2(cosf(ang), sinf(ang));
    if (t < 512) {
        float a2 = -0.5f * S;
        #pragma unroll
        for (int j = 0; j < 9; ++j) if ((t >> j) & 1) a2 += pw[10 + j];
        Phh[t] = make_float2(cosf(a2), sinf(a2));
    }
}

// ---- LDS transpose passes (bank-floor XOR swizzles) ------------------------
__device__ __forceinline__ void pass_w1(float2* buf, int t,
                                        float2 a0, float2 a1, float2 a2, float2 a3) {
    int mb = ((t >> 4) & 3) | (((t >> 6) & 0xF) << 2) |
             (((t >> 2) & 3) << 6) | ((t & 3) << 10);
    int pb = mb ^ ((t & 3) << 2) ^ (((t >> 2) & 3) << 4);
    buf[pb] = a0; buf[pb | 256] = a1; buf[pb | 512] = a2; buf[pb | 768] = a3;
}
__device__ __forceinline__ void pass_r1(const float2* buf, int t,
                                        float2& a0, float2& a1, float2& a2, float2& a3) {
    int rb = (4 * t) ^ (((t >> 8) & 3) << 2) ^ (((t >> 4) & 3) << 4);
    const float4* b4 = (const float4*)(buf + rb);
    float4 u = b4[0], w = b4[1];
    a0 = make_float2(u.x, u.y); a1 = make_float2(u.z, u.w);
    a2 = make_float2(w.x, w.y); a3 = make_float2(w.z, w.w);
}
__device__ __forceinline__ int q_nb(int t) {
    return ((t >> 6) & 0xF) | (((t >> 4) & 3) << 4) | ((t & 0xF) << 8);
}
__device__ __forceinline__ void pass_w2(float2* buf, int t,
                                        float2 a0, float2 a1, float2 a2, float2 a3) {
    int nb = q_nb(t);
    int qb = nb ^ (t & 3) ^ (((t >> 2) & 3) << 2);
    buf[qb] = a0; buf[qb ^ 0x50] = a1; buf[qb ^ 0xA0] = a2; buf[qb ^ 0xF0] = a3;
}
__device__ __forceinline__ void pass_r2(const float2* buf, int t,
                                        float2& a0, float2& a1, float2& a2, float2& a3) {
    int rb = (4 * t) ^ (((t >> 8) & 3) << 2) ^ (((t >> 4) & 3) << 4);
    const float4* b4 = (const float4*)(buf + rb);
    float4 u = b4[0], w = b4[1];
    float2 r0 = make_float2(u.x, u.y), r1 = make_float2(u.z, u.w),
           r2 = make_float2(w.x, w.y), r3 = make_float2(w.z, w.w);
    int k = (t >> 6) & 3;                       // wave-uniform in-quad xor
    if (k & 1) { float2 x = r0; r0 = r1; r1 = x; x = r2; r2 = r3; r3 = x; }
    if (k & 2) { float2 x = r0; r0 = r2; r2 = x; x = r1; r1 = r3; r3 = x; }
    a0 = r0; a1 = r1; a2 = r2; a3 = r3;
}

__device__ __forceinline__ int hi_x(int n, int blk) {
    return ((n >> 3) << 11) | (blk << 3) | (n & 7);
}

// ---- device-scope grid barrier (monotonic counter, phase = 1,2,...) --------
__device__ __forceinline__ void gbar(unsigned* cnt, unsigned phase) {
    __syncthreads();                       // drains vmcnt: block's stores in L2
    if (threadIdx.x == 0) {
        __threadfence();                   // release: L2 writeback (agent scope)
        atomicAdd(cnt, 1u);
        const unsigned target = phase * (unsigned)NBLK;
        while (atomicAdd(cnt, 0u) < target) __builtin_amdgcn_s_sleep(1);
        __threadfence();                   // acquire: invalidate stale caches
    }
    __syncthreads();
}

// ---------------- LOW sweep: tile = contiguous 4096 amps --------------------
// Uses Plo/Phh built by the PREVIOUS sweep. Tail builds next sweep's D (phN).
template<bool LAST>
__device__ __forceinline__ void sweep_low(float2* __restrict__ psi,
        const float2* cA, const float2* cB, const float* phN,
        float* __restrict__ outP,
        float2* bufA, float2* bufB, float2* Plo, float2* Phh, int t, int blk) {
    const float4* gp = (const float4*)(psi + (blk << 12));
    float4 v0 = gp[2 * t], v1 = gp[2 * t + 1];

    float2 a0 = make_float2(v0.x, v0.y), a1 = make_float2(v0.z, v0.w),
           a2 = make_float2(v1.x, v1.y), a3 = make_float2(v1.z, v1.w);

    // phase1 @L0: A flat 0..5
    rot4c(a0, a1, a2, a3, cA[0], cA[1]);
    lrot4<1>(a0, a1, a2, a3, cA[2], t);
    lrot4<2>(a0, a1, a2, a3, cA[3], t);
    lrot4<4>(a0, a1, a2, a3, cA[4], t);
    lrot4<8>(a0, a1, a2, a3, cA[5], t);

    pass_w1(bufA, t, a0, a1, a2, a3);
    __syncthreads();                     // bar1
    pass_r1(bufA, t, a0, a1, a2, a3);

    // phase2 @Q: A flat 6..10
    rot4c(a0, a1, a2, a3, cA[6], cA[7]);
    lrot4<1>(a0, a1, a2, a3, cA[8], t);
    lrot4<2>(a0, a1, a2, a3, cA[9], t);
    lrot4<4>(a0, a1, a2, a3, cA[10], t);

    int nb = q_nb(t);
    if (LAST) {
        // |amp|^2 -> float buffer -> coalesced float4 out (D_7 elided)
        float* bf = (float*)bufB;
        int qb = nb ^ (t & 3) ^ (((t >> 2) & 3) << 2);
        bf[qb]        = a0.x * a0.x + a0.y * a0.y;
        bf[qb ^ 0x50] = a1.x * a1.x + a1.y * a1.y;
        bf[qb ^ 0xA0] = a2.x * a2.x + a2.y * a2.y;
        bf[qb ^ 0xF0] = a3.x * a3.x + a3.y * a3.y;
        __syncthreads();
        int rb = (4 * t) ^ (((t >> 8) & 3) << 2) ^ (((t >> 4) & 3) << 4);
        float4 u = *(const float4*)(bf + rb);
        int k = (t >> 6) & 3;
        if (k & 1) { float x = u.x; u.x = u.y; u.y = x; x = u.z; u.z = u.w; u.w = x; }
        if (k & 2) { float x = u.x; u.x = u.z; u.z = x; x = u.y; u.y = u.w; u.w = x; }
        *(float4*)(outP + (blk << 12) + 4 * t) = u;
    } else {
        int xb = blk << 12;
        a0 = cmulf(a0, dphase(xb | nb,        Plo, Phh));
        a1 = cmulf(a1, dphase(xb | nb | 0x40, Plo, Phh));
        a2 = cmulf(a2, dphase(xb | nb | 0x80, Plo, Phh));
        a3 = cmulf(a3, dphase(xb | nb | 0xC0, Plo, Phh));
        // B flat 6..11 (still in Q)
        rot4c(a0, a1, a2, a3, cB[6], cB[7]);
        lrot4<1>(a0, a1, a2, a3, cB[8], t);
        lrot4<2>(a0, a1, a2, a3, cB[9], t);
        lrot4<4>(a0, a1, a2, a3, cB[10], t);
        lrot4<8>(a0, a1, a2, a3, cB[11], t);

        pass_w2(bufB, t, a0, a1, a2, a3);
        __syncthreads();                 // bar2 (also: Plo dead after this)
        pass_r2(bufB, t, a0, a1, a2, a3);

        // phase3 @L0: B flat 0..5
        lrot4<1>(a0, a1, a2, a3, cB[2], t);
        lrot4<2>(a0, a1, a2, a3, cB[3], t);
        lrot4<4>(a0, a1, a2, a3, cB[4], t);
        lrot4<8>(a0, a1, a2, a3, cB[5], t);
        rot4c(a0, a1, a2, a3, cB[0], cB[1]);
        float4* op = (float4*)(psi + (blk << 12));
        op[2 * t]     = make_float4(a0.x, a0.y, a1.x, a1.y);
        op[2 * t + 1] = make_float4(a2.x, a2.y, a3.x, a3.y);
        if (phN) build_D(Plo, Phh, phN, t);   // next sweep's diagonal
    }
}

// ---------------- HI sweep: n3..n11 = flat 11..19, n0..n2 = flat 0..2 -------
__device__ __forceinline__ void sweep_hi(float2* __restrict__ psi,
        const float2* cA, const float2* cB, const float* phN,
        float2* bufA, float2* bufB, float2* Plo, float2* Phh, int t, int blk) {
    const int ga = ((t >> 1) << 11) | (blk << 3) | ((t & 1) << 2);  // n = 4t+j

    const float4* gp = (const float4*)(psi + ga);
    float4 v0 = gp[0], v1 = gp[1];

    float2 a0 = make_float2(v0.x, v0.y), a1 = make_float2(v0.z, v0.w),
           a2 = make_float2(v1.x, v1.y), a3 = make_float2(v1.z, v1.w);

    // phase1 @H0: A flat 12,13 (n4,n5)
    lrot4<4>(a0, a1, a2, a3, cA[12], t);
    lrot4<8>(a0, a1, a2, a3, cA[13], t);

    pass_w1(bufA, t, a0, a1, a2, a3);
    __syncthreads();                     // bar1
    pass_r1(bufA, t, a0, a1, a2, a3);

    // phase2 @Q: A flat 14..19 (n6..n11)
    rot4c(a0, a1, a2, a3, cA[14], cA[15]);
    lrot4<1>(a0, a1, a2, a3, cA[16], t);
    lrot4<2>(a0, a1, a2, a3, cA[17], t);
    lrot4<4>(a0, a1, a2, a3, cA[18], t);
    lrot4<8>(a0, a1, a2, a3, cA[19], t);

    int nb = q_nb(t);
    a0 = cmulf(a0, dphase(hi_x(nb,        blk), Plo, Phh));
    a1 = cmulf(a1, dphase(hi_x(nb | 0x40, blk), Plo, Phh));
    a2 = cmulf(a2, dphase(hi_x(nb | 0x80, blk), Plo, Phh));
    a3 = cmulf(a3, dphase(hi_x(nb | 0xC0, blk), Plo, Phh));

    // B flat 14..19 (still in Q)
    rot4c(a0, a1, a2, a3, cB[14], cB[15]);
    lrot4<1>(a0, a1, a2, a3, cB[16], t);
    lrot4<2>(a0, a1, a2, a3, cB[17], t);
    lrot4<4>(a0, a1, a2, a3, cB[18], t);
    lrot4<8>(a0, a1, a2, a3, cB[19], t);

    pass_w2(bufB, t, a0, a1, a2, a3);
    __syncthreads();                     // bar2 (Plo dead after this)
    pass_r2(bufB, t, a0, a1, a2, a3);

    // phase3 @H0: B flat 11,12,13 (n3,n4,n5)
    lrot4<2>(a0, a1, a2, a3, cB[11], t);
    lrot4<4>(a0, a1, a2, a3, cB[12], t);
    lrot4<8>(a0, a1, a2, a3, cB[13], t);

    float4* gp2 = (float4*)(psi + ga);
    gp2[0] = make_float4(a0.x, a0.y, a1.x, a1.y);
    gp2[1] = make_float4(a2.x, a2.y, a3.x, a3.y);
    if (phN) build_D(Plo, Phh, phN, t);      // next sweep's diagonal
}

// ---------------- INIT sweep: synth Ry_0|0>, D_0, B = Ry_1 flat 11..19 ------
// Also dumps cos/sin(theta/2) for all 8 layers to cw. Tail builds D_1.
__device__ __forceinline__ void sweep_init(float2* __restrict__ psi,
        const float* __restrict__ th, const float* __restrict__ ph0,
        const float* phN, float2* __restrict__ cw,
        float2* bufA, float2* bufB, float2* Plo, float2* Phh, int t, int blk) {
    float* Alo = (float*)bufA;           // floats [0..1023]
    float* Ahi = Alo + 1024;             // floats [1024..2047]
    float2* cAi = bufA + 1024;           // float2 [1024..1043]
    float2* cBi = bufA + 1056;           // float2 [1056..1075]
    const int ga = ((t >> 1) << 11) | (blk << 3) | ((t & 1) << 2);

    if (t < 256) {
        int l = t >> 5, f = t & 31;
        if (f < 20) {
            double a = 0.5 * (double)th[l * 20 + 19 - f];
            float2 w = make_float2((float)cos(a), (float)sin(a));
            cw[l * 20 + f] = w;
            if (l == 0) cAi[f] = w;
            else if (l == 1) cBi[f] = w;
        }
    }
    __syncthreads();                     // bar0: cAi/cBi ready

    build_D(Plo, Phh, ph0, t);
    {
        float pl = 1.f, ph2 = 1.f;
        #pragma unroll
        for (int j = 0; j < 10; ++j) {
            pl  *= ((t >> j) & 1) ? cAi[j].y      : cAi[j].x;
            ph2 *= ((t >> j) & 1) ? cAi[10 + j].y : cAi[10 + j].x;
        }
        Alo[t] = pl; Ahi[t] = ph2;
    }
    __syncthreads();                     // bar1: tables ready

    // synth product state directly in Q layout, D_0 fused
    int nb = q_nb(t);
    float2 a0, a1, a2, a3;
    {
        int x0 = hi_x(nb, blk),        x1 = hi_x(nb | 0x40, blk),
            x2 = hi_x(nb | 0x80, blk), x3 = hi_x(nb | 0xC0, blk);
        float m0 = Alo[x0 & 1023] * Ahi[x0 >> 10];
        float m1 = Alo[x1 & 1023] * Ahi[x1 >> 10];
        float m2 = Alo[x2 & 1023] * Ahi[x2 >> 10];
        float m3 = Alo[x3 & 1023] * Ahi[x3 >> 10];
        float2 d0 = dphase(x0, Plo, Phh), d1 = dphase(x1, Plo, Phh),
               d2 = dphase(x2, Plo, Phh), d3 = dphase(x3, Plo, Phh);
        a0 = make_float2(m0 * d0.x, m0 * d0.y);
        a1 = make_float2(m1 * d1.x, m1 * d1.y);
        a2 = make_float2(m2 * d2.x, m2 * d2.y);
        a3 = make_float2(m3 * d3.x, m3 * d3.y);
    }

    // B = Ry_1 flat 14..19 in Q
    rot4c(a0, a1, a2, a3, cBi[14], cBi[15]);
    lrot4<1>(a0, a1, a2, a3, cBi[16], t);
    lrot4<2>(a0, a1, a2, a3, cBi[17], t);
    lrot4<4>(a0, a1, a2, a3, cBi[18], t);
    lrot4<8>(a0, a1, a2, a3, cBi[19], t);

    pass_w2(bufB, t, a0, a1, a2, a3);
    __syncthreads();                     // bar2 (Plo/cBi live: cBi reads below
                                         // are pre-bar2-written, safe; Plo dead)
    pass_r2(bufB, t, a0, a1, a2, a3);

    // phase3 @H0: B flat 11,12,13
    lrot4<2>(a0, a1, a2, a3, cBi[11], t);
    lrot4<4>(a0, a1, a2, a3, cBi[12], t);
    lrot4<8>(a0, a1, a2, a3, cBi[13], t);

    float4* gp2 = (float4*)(psi + ga);
    gp2[0] = make_float4(a0.x, a0.y, a1.x, a1.y);
    gp2[1] = make_float4(a2.x, a2.y, a3.x, a3.y);
    if (phN) build_D(Plo, Phh, phN, t);      // D_1 for sweep 1
}

// ---------------- mega-kernel: 8 sweeps, 7 grid barriers --------------------
__global__ __launch_bounds__(1024)
void mega_kernel(float2* __restrict__ psi, const float* __restrict__ th,
                 const float* __restrict__ ph, float2* __restrict__ cw,
                 float* __restrict__ outP, unsigned* __restrict__ bar) {
    __shared__ __align__(16) float2 bufA[4096];
    __shared__ __align__(16) float2 bufB[4096];
    __shared__ float2 Plo[1024];
    __shared__ float2 Phh[512];
    const int t = threadIdx.x, blk = blockIdx.x;

    sweep_init(psi, th, ph, ph + 19, cw, bufA, bufB, Plo, Phh, t, blk);
    gbar(bar, 1);
    sweep_low<false>(psi, cw + 20,  cw + 40,  ph + 38, nullptr, bufA, bufB, Plo, Phh, t, blk);
    gbar(bar, 2);
    sweep_hi        (psi, cw + 40,  cw + 60,  ph + 57,          bufA, bufB, Plo, Phh, t, blk);
    gbar(bar, 3);
    sweep_low<false>(psi, cw + 60,  cw + 80,  ph + 76, nullptr, bufA, bufB, Plo, Phh, t, blk);
    gbar(bar, 4);
    sweep_hi        (psi, cw + 80,  cw + 100, ph + 95,          bufA, bufB, Plo, Phh, t, blk);
    gbar(bar, 5);
    sweep_low<false>(psi, cw + 100, cw + 120, ph + 114, nullptr, bufA, bufB, Plo, Phh, t, blk);
    gbar(bar, 6);
    sweep_hi        (psi, cw + 120, cw + 140, nullptr,          bufA, bufB, Plo, Phh, t, blk);
    gbar(bar, 7);
    sweep_low<true> (psi, cw + 140, cw + 140, nullptr, outP,    bufA, bufB, Plo, Phh, t, blk);
}

extern "C" void kernel_launch(void* const* d_in, const int* in_sizes, int n_in,
                              void* d_out, int out_size, void* d_ws, size_t ws_size,
                              hipStream_t stream) {
    (void)in_sizes; (void)n_in; (void)out_size; (void)ws_size;
    const float* th = (const float*)d_in[0];   // (8,20)
    const float* ph = (const float*)d_in[1];   // (8,19)
    float2* psi = (float2*)d_ws;               // 2^20 complex64 = 8 MB
    float2* cw  = (float2*)((char*)d_ws + (8u << 20));          // coeff dump
    unsigned* bar = (unsigned*)((char*)d_ws + (8u << 20) + 4096); // barrier
    float* out = (float*)d_out;

    hipMemsetAsync(bar, 0, 64, stream);
    mega_kernel<<<NBLK, 1024, 0, stream>>>(psi, th, ph, cw, out, bar);
}

// Round 5
// 182.800 us; speedup vs baseline: 1.3878x; 1.3878x over previous
//
#include <hip/hip_runtime.h>

// 20-qubit statevector, 8 layers {Ry x20, CZ chain, Rzz chain}, out = |psi|^2.
// R5 = R4 with compile fixes: __hip_atomic_fence -> __builtin_amdgcn_fence,
// (void)hipMemsetAsync. Persistent mega-kernel, 8 sweeps, 7 grid barriers:
//  - two-level arrival (8 group counters on separate cachelines -> root),
//  - release word + LOAD-spin (agent-scope atomic loads; no RMW storm),
//  - arrive-early / build_D(next) / wait-late to hide table sincos.
// Per sweep: 4 amps/thread in registers; rotations on reg bits (free) and
// lane bits (DPP, VALU pipe); wave bits moved by TWO XOR-swizzled LDS
// transpose passes.
// Layouts (tile index n[11:0], thread t[9:0], amp j[1:0]):
//  L0: reg={n1,n0} lanes={n7..n2} wave={n11..n8}   (global-coalesced order)
//  Q : reg={n7,n6} lanes={n5,n4 parked | n11..n8}  wave={n3..n0}
// DPP semantics: row_shr:N = from lane i-N, row_shl:N = from lane i+N.

#define QN 20
#define NBLK 256
#define GRPS 8
#define BPG (NBLK / GRPS)          // 32 blocks per group

__device__ __forceinline__ float2 cmulf(float2 a, float2 b) {
    return make_float2(a.x * b.x - a.y * b.y, a.x * b.y + a.y * b.x);
}

// ---- rotation on register bits: w = (cos, sin) -----------------------------
__device__ __forceinline__ void rot2c(float2& x0, float2& x1, float2 w) {
    float2 t0 = make_float2(w.x * x0.x - w.y * x1.x, w.x * x0.y - w.y * x1.y);
    float2 t1 = make_float2(w.y * x0.x + w.x * x1.x, w.y * x0.y + w.x * x1.y);
    x0 = t0; x1 = t1;
}
__device__ __forceinline__ void rot4c(float2& a0, float2& a1, float2& a2, float2& a3,
                                      float2 wa, float2 wb) {
    rot2c(a0, a1, wa); rot2c(a2, a3, wa);
    rot2c(a0, a2, wb); rot2c(a1, a3, wb);
}

// ---- DPP cross-lane partner fetch (xor distance X in {1,2,4,8}) ------------
template<int X>
__device__ __forceinline__ float2 xpart(float2 v, int t) {
    int sx = __float_as_int(v.x), sy = __float_as_int(v.y);
    if constexpr (X == 4) {
        // row_shr:4 (0x114): lane i <- i-4 (valid for t&4=1); row_shl:4
        // (0x104): lane i <- i+4 (valid for t&4=0); select by side.
        int ax = __builtin_amdgcn_update_dpp(sx, sx, 0x114, 0xF, 0xF, false);
        int ay = __builtin_amdgcn_update_dpp(sy, sy, 0x114, 0xF, 0xF, false);
        int bx = __builtin_amdgcn_update_dpp(sx, sx, 0x104, 0xF, 0xF, false);
        int by = __builtin_amdgcn_update_dpp(sy, sy, 0x104, 0xF, 0xF, false);
        bool hi = (t & 4) != 0;
        return make_float2(__int_as_float(hi ? ax : bx), __int_as_float(hi ? ay : by));
    } else {
        // xor1: quad_perm[1,0,3,2]=0xB1; xor2: quad_perm[2,3,0,1]=0x4E;
        // xor8: row_ror:8=0x128 ((i+8)%16 == i^8 within a 16-row)
        constexpr int ctrl = (X == 1) ? 0xB1 : (X == 2) ? 0x4E : 0x128;
        return make_float2(
            __int_as_float(__builtin_amdgcn_update_dpp(sx, sx, ctrl, 0xF, 0xF, false)),
            __int_as_float(__builtin_amdgcn_update_dpp(sy, sy, ctrl, 0xF, 0xF, false)));
    }
}

// Ry on a lane bit: own' = c*own + (side? +s : -s)*partner
template<int X>
__device__ __forceinline__ void lrot4(float2& a0, float2& a1, float2& a2, float2& a3,
                                      float2 w, int t) {
    float ss = (t & X) ? w.y : -w.y;
    float2 p0 = xpart<X>(a0, t), p1 = xpart<X>(a1, t),
           p2 = xpart<X>(a2, t), p3 = xpart<X>(a3, t);
    a0 = make_float2(fmaf(ss, p0.x, w.x * a0.x), fmaf(ss, p0.y, w.x * a0.y));
    a1 = make_float2(fmaf(ss, p1.x, w.x * a1.x), fmaf(ss, p1.y, w.x * a1.y));
    a2 = make_float2(fmaf(ss, p2.x, w.x * a2.x), fmaf(ss, p2.y, w.x * a2.y));
    a3 = make_float2(fmaf(ss, p3.x, w.x * a3.x), fmaf(ss, p3.y, w.x * a3.y));
}

// ---- diagonal (CZ chain + Rzz chain) phase ---------------------------------
__device__ __forceinline__ float2 dphase(int x, const float2* Plo, const float2* Phh) {
    int y = (x ^ (x >> 1)) & 0x7FFFF;
    float2 p = cmulf(Plo[y & 1023], Phh[y >> 10]);
    int sgn = (__popc(x & (x >> 1) & 0x7FFFF) & 1) << 31;
    p.x = __int_as_float(__float_as_int(p.x) ^ sgn);
    p.y = __int_as_float(__float_as_int(p.y) ^ sgn);
    return p;
}

__device__ __forceinline__ void build_D(float2* Plo, float2* Phh,
                                        const float* __restrict__ ph, int t) {
    float pw[19];
    #pragma unroll
    for (int j = 0; j < 19; ++j) pw[j] = ph[18 - j];   // uniform loads
    float S = 0.f;
    #pragma unroll
    for (int j = 0; j < 19; ++j) S += pw[j];
    float ang = 0.f;
    #pragma unroll
    for (int j = 0; j < 10; ++j) if ((t >> j) & 1) ang += pw[j];
    Plo[t] = make_float2(cosf(ang), sinf(ang));
    if (t < 512) {
        float a2 = -0.5f * S;
        #pragma unroll
        for (int j = 0; j < 9; ++j) if ((t >> j) & 1) a2 += pw[10 + j];
        Phh[t] = make_float2(cosf(a2), sinf(a2));
    }
}

// ---- LDS transpose passes (bank-floor XOR swizzles) ------------------------
__device__ __forceinline__ void pass_w1(float2* buf, int t,
                                        float2 a0, float2 a1, float2 a2, float2 a3) {
    int mb = ((t >> 4) & 3) | (((t >> 6) & 0xF) << 2) |
             (((t >> 2) & 3) << 6) | ((t & 3) << 10);
    int pb = mb ^ ((t & 3) << 2) ^ (((t >> 2) & 3) << 4);
    buf[pb] = a0; buf[pb | 256] = a1; buf[pb | 512] = a2; buf[pb | 768] = a3;
}
__device__ __forceinline__ void pass_r1(const float2* buf, int t,
                                        float2& a0, float2& a1, float2& a2, float2& a3) {
    int rb = (4 * t) ^ (((t >> 8) & 3) << 2) ^ (((t >> 4) & 3) << 4);
    const float4* b4 = (const float4*)(buf + rb);
    float4 u = b4[0], w = b4[1];
    a0 = make_float2(u.x, u.y); a1 = make_float2(u.z, u.w);
    a2 = make_float2(w.x, w.y); a3 = make_float2(w.z, w.w);
}
__device__ __forceinline__ int q_nb(int t) {
    return ((t >> 6) & 0xF) | (((t >> 4) & 3) << 4) | ((t & 0xF) << 8);
}
__device__ __forceinline__ void pass_w2(float2* buf, int t,
                                        float2 a0, float2 a1, float2 a2, float2 a3) {
    int nb = q_nb(t);
    int qb = nb ^ (t & 3) ^ (((t >> 2) & 3) << 2);
    buf[qb] = a0; buf[qb ^ 0x50] = a1; buf[qb ^ 0xA0] = a2; buf[qb ^ 0xF0] = a3;
}
__device__ __forceinline__ void pass_r2(const float2* buf, int t,
                                        float2& a0, float2& a1, float2& a2, float2& a3) {
    int rb = (4 * t) ^ (((t >> 8) & 3) << 2) ^ (((t >> 4) & 3) << 4);
    const float4* b4 = (const float4*)(buf + rb);
    float4 u = b4[0], w = b4[1];
    float2 r0 = make_float2(u.x, u.y), r1 = make_float2(u.z, u.w),
           r2 = make_float2(w.x, w.y), r3 = make_float2(w.z, w.w);
    int k = (t >> 6) & 3;                       // wave-uniform in-quad xor
    if (k & 1) { float2 x = r0; r0 = r1; r1 = x; x = r2; r2 = r3; r3 = x; }
    if (k & 2) { float2 x = r0; r0 = r2; r2 = x; x = r1; r1 = r3; r3 = x; }
    a0 = r0; a1 = r1; a2 = r2; a3 = r3;
}

__device__ __forceinline__ int hi_x(int n, int blk) {
    return ((n >> 3) << 11) | (blk << 3) | (n & 7);
}

// ---- two-level grid barrier: group counters -> root -> release word --------
// B layout (unsigned words): grp g at B[g*32] (128 B apart), root at B[512],
// release at B[544]. All monotonic; no reset. Load-spin on release only.
__device__ __forceinline__ void gbar_arrive(unsigned* B, unsigned phase) {
    __syncthreads();                   // all block stores issued & in L2
    if (threadIdx.x == 0) {
        unsigned g = (unsigned)blockIdx.x & (GRPS - 1);
        unsigned v = __hip_atomic_fetch_add(B + g * 32, 1u,
                         __ATOMIC_ACQ_REL, __HIP_MEMORY_SCOPE_AGENT);
        if (v == phase * BPG - 1) {    // last of group this phase
            unsigned r = __hip_atomic_fetch_add(B + 512, 1u,
                             __ATOMIC_ACQ_REL, __HIP_MEMORY_SCOPE_AGENT);
            if (r == phase * GRPS - 1) // last group: publish
                __hip_atomic_store(B + 544, phase,
                                   __ATOMIC_RELEASE, __HIP_MEMORY_SCOPE_AGENT);
        }
    }
}
__device__ __forceinline__ void gbar_wait(unsigned* B, unsigned phase) {
    if (threadIdx.x == 0) {
        while (__hip_atomic_load(B + 544, __ATOMIC_RELAXED,
                                 __HIP_MEMORY_SCOPE_AGENT) < phase)
            __builtin_amdgcn_s_sleep(2);
        __builtin_amdgcn_fence(__ATOMIC_ACQUIRE, "agent");
    }
    __syncthreads();
}

// ---------------- LOW sweep: tile = contiguous 4096 amps --------------------
// Uses Plo/Phh built before this sweep (between barriers).
template<bool LAST>
__device__ __forceinline__ void sweep_low(float2* __restrict__ psi,
        const float2* cA, const float2* cB, float* __restrict__ outP,
        float2* bufA, float2* bufB, float2* Plo, float2* Phh, int t, int blk) {
    const float4* gp = (const float4*)(psi + (blk << 12));
    float4 v0 = gp[2 * t], v1 = gp[2 * t + 1];

    float2 a0 = make_float2(v0.x, v0.y), a1 = make_float2(v0.z, v0.w),
           a2 = make_float2(v1.x, v1.y), a3 = make_float2(v1.z, v1.w);

    // phase1 @L0: A flat 0..5
    rot4c(a0, a1, a2, a3, cA[0], cA[1]);
    lrot4<1>(a0, a1, a2, a3, cA[2], t);
    lrot4<2>(a0, a1, a2, a3, cA[3], t);
    lrot4<4>(a0, a1, a2, a3, cA[4], t);
    lrot4<8>(a0, a1, a2, a3, cA[5], t);

    pass_w1(bufA, t, a0, a1, a2, a3);
    __syncthreads();                     // bar1
    pass_r1(bufA, t, a0, a1, a2, a3);

    // phase2 @Q: A flat 6..10
    rot4c(a0, a1, a2, a3, cA[6], cA[7]);
    lrot4<1>(a0, a1, a2, a3, cA[8], t);
    lrot4<2>(a0, a1, a2, a3, cA[9], t);
    lrot4<4>(a0, a1, a2, a3, cA[10], t);

    int nb = q_nb(t);
    if (LAST) {
        // |amp|^2 -> float buffer -> coalesced float4 out (D_7 elided)
        float* bf = (float*)bufB;
        int qb = nb ^ (t & 3) ^ (((t >> 2) & 3) << 2);
        bf[qb]        = a0.x * a0.x + a0.y * a0.y;
        bf[qb ^ 0x50] = a1.x * a1.x + a1.y * a1.y;
        bf[qb ^ 0xA0] = a2.x * a2.x + a2.y * a2.y;
        bf[qb ^ 0xF0] = a3.x * a3.x + a3.y * a3.y;
        __syncthreads();
        int rb = (4 * t) ^ (((t >> 8) & 3) << 2) ^ (((t >> 4) & 3) << 4);
        float4 u = *(const float4*)(bf + rb);
        int k = (t >> 6) & 3;
        if (k & 1) { float x = u.x; u.x = u.y; u.y = x; x = u.z; u.z = u.w; u.w = x; }
        if (k & 2) { float x = u.x; u.x = u.z; u.z = x; x = u.y; u.y = u.w; u.w = x; }
        *(float4*)(outP + (blk << 12) + 4 * t) = u;
    } else {
        int xb = blk << 12;
        a0 = cmulf(a0, dphase(xb | nb,        Plo, Phh));
        a1 = cmulf(a1, dphase(xb | nb | 0x40, Plo, Phh));
        a2 = cmulf(a2, dphase(xb | nb | 0x80, Plo, Phh));
        a3 = cmulf(a3, dphase(xb | nb | 0xC0, Plo, Phh));
        // B flat 6..11 (still in Q)
        rot4c(a0, a1, a2, a3, cB[6], cB[7]);
        lrot4<1>(a0, a1, a2, a3, cB[8], t);
        lrot4<2>(a0, a1, a2, a3, cB[9], t);
        lrot4<4>(a0, a1, a2, a3, cB[10], t);
        lrot4<8>(a0, a1, a2, a3, cB[11], t);

        pass_w2(bufB, t, a0, a1, a2, a3);
        __syncthreads();                 // bar2
        pass_r2(bufB, t, a0, a1, a2, a3);

        // phase3 @L0: B flat 0..5
        lrot4<1>(a0, a1, a2, a3, cB[2], t);
        lrot4<2>(a0, a1, a2, a3, cB[3], t);
        lrot4<4>(a0, a1, a2, a3, cB[4], t);
        lrot4<8>(a0, a1, a2, a3, cB[5], t);
        rot4c(a0, a1, a2, a3, cB[0], cB[1]);
        float4* op = (float4*)(psi + (blk << 12));
        op[2 * t]     = make_float4(a0.x, a0.y, a1.x, a1.y);
        op[2 * t + 1] = make_float4(a2.x, a2.y, a3.x, a3.y);
    }
}

// ---------------- HI sweep: n3..n11 = flat 11..19, n0..n2 = flat 0..2 -------
__device__ __forceinline__ void sweep_hi(float2* __restrict__ psi,
        const float2* cA, const float2* cB,
        float2* bufA, float2* bufB, float2* Plo, float2* Phh, int t, int blk) {
    const int ga = ((t >> 1) << 11) | (blk << 3) | ((t & 1) << 2);  // n = 4t+j

    const float4* gp = (const float4*)(psi + ga);
    float4 v0 = gp[0], v1 = gp[1];

    float2 a0 = make_float2(v0.x, v0.y), a1 = make_float2(v0.z, v0.w),
           a2 = make_float2(v1.x, v1.y), a3 = make_float2(v1.z, v1.w);

    // phase1 @H0: A flat 12,13 (n4,n5)
    lrot4<4>(a0, a1, a2, a3, cA[12], t);
    lrot4<8>(a0, a1, a2, a3, cA[13], t);

    pass_w1(bufA, t, a0, a1, a2, a3);
    __syncthreads();                     // bar1
    pass_r1(bufA, t, a0, a1, a2, a3);

    // phase2 @Q: A flat 14..19 (n6..n11)
    rot4c(a0, a1, a2, a3, cA[14], cA[15]);
    lrot4<1>(a0, a1, a2, a3, cA[16], t);
    lrot4<2>(a0, a1, a2, a3, cA[17], t);
    lrot4<4>(a0, a1, a2, a3, cA[18], t);
    lrot4<8>(a0, a1, a2, a3, cA[19], t);

    int nb = q_nb(t);
    a0 = cmulf(a0, dphase(hi_x(nb,        blk), Plo, Phh));
    a1 = cmulf(a1, dphase(hi_x(nb | 0x40, blk), Plo, Phh));
    a2 = cmulf(a2, dphase(hi_x(nb | 0x80, blk), Plo, Phh));
    a3 = cmulf(a3, dphase(hi_x(nb | 0xC0, blk), Plo, Phh));

    // B flat 14..19 (still in Q)
    rot4c(a0, a1, a2, a3, cB[14], cB[15]);
    lrot4<1>(a0, a1, a2, a3, cB[16], t);
    lrot4<2>(a0, a1, a2, a3, cB[17], t);
    lrot4<4>(a0, a1, a2, a3, cB[18], t);
    lrot4<8>(a0, a1, a2, a3, cB[19], t);

    pass_w2(bufB, t, a0, a1, a2, a3);
    __syncthreads();                     // bar2
    pass_r2(bufB, t, a0, a1, a2, a3);

    // phase3 @H0: B flat 11,12,13 (n3,n4,n5)
    lrot4<2>(a0, a1, a2, a3, cB[11], t);
    lrot4<4>(a0, a1, a2, a3, cB[12], t);
    lrot4<8>(a0, a1, a2, a3, cB[13], t);

    float4* gp2 = (float4*)(psi + ga);
    gp2[0] = make_float4(a0.x, a0.y, a1.x, a1.y);
    gp2[1] = make_float4(a2.x, a2.y, a3.x, a3.y);
}

// ---------------- INIT sweep: synth Ry_0|0>, D_0, B = Ry_1 flat 11..19 ------
// Also dumps cos/sin(theta/2) for all 8 layers to cw.
__device__ __forceinline__ void sweep_init(float2* __restrict__ psi,
        const float* __restrict__ th, const float* __restrict__ ph0,
        float2* __restrict__ cw,
        float2* bufA, float2* bufB, float2* Plo, float2* Phh, int t, int blk) {
    float* Alo = (float*)bufA;           // floats [0..1023]
    float* Ahi = Alo + 1024;             // floats [1024..2047]
    float2* cAi = bufA + 1024;           // float2 [1024..1043]
    float2* cBi = bufA + 1056;           // float2 [1056..1075]
    const int ga = ((t >> 1) << 11) | (blk << 3) | ((t & 1) << 2);

    if (t < 256) {
        int l = t >> 5, f = t & 31;
        if (f < 20) {
            double a = 0.5 * (double)th[l * 20 + 19 - f];
            float2 w = make_float2((float)cos(a), (float)sin(a));
            cw[l * 20 + f] = w;
            if (l == 0) cAi[f] = w;
            else if (l == 1) cBi[f] = w;
        }
    }
    __syncthreads();                     // bar0: cAi/cBi ready

    build_D(Plo, Phh, ph0, t);
    {
        float pl = 1.f, ph2 = 1.f;
        #pragma unroll
        for (int j = 0; j < 10; ++j) {
            pl  *= ((t >> j) & 1) ? cAi[j].y      : cAi[j].x;
            ph2 *= ((t >> j) & 1) ? cAi[10 + j].y : cAi[10 + j].x;
        }
        Alo[t] = pl; Ahi[t] = ph2;
    }
    __syncthreads();                     // bar1: tables ready

    // synth product state directly in Q layout, D_0 fused
    int nb = q_nb(t);
    float2 a0, a1, a2, a3;
    {
        int x0 = hi_x(nb, blk),        x1 = hi_x(nb | 0x40, blk),
            x2 = hi_x(nb | 0x80, blk), x3 = hi_x(nb | 0xC0, blk);
        float m0 = Alo[x0 & 1023] * Ahi[x0 >> 10];
        float m1 = Alo[x1 & 1023] * Ahi[x1 >> 10];
        float m2 = Alo[x2 & 1023] * Ahi[x2 >> 10];
        float m3 = Alo[x3 & 1023] * Ahi[x3 >> 10];
        float2 d0 = dphase(x0, Plo, Phh), d1 = dphase(x1, Plo, Phh),
               d2 = dphase(x2, Plo, Phh), d3 = dphase(x3, Plo, Phh);
        a0 = make_float2(m0 * d0.x, m0 * d0.y);
        a1 = make_float2(m1 * d1.x, m1 * d1.y);
        a2 = make_float2(m2 * d2.x, m2 * d2.y);
        a3 = make_float2(m3 * d3.x, m3 * d3.y);
    }

    // B = Ry_1 flat 14..19 in Q
    rot4c(a0, a1, a2, a3, cBi[14], cBi[15]);
    lrot4<1>(a0, a1, a2, a3, cBi[16], t);
    lrot4<2>(a0, a1, a2, a3, cBi[17], t);
    lrot4<4>(a0, a1, a2, a3, cBi[18], t);
    lrot4<8>(a0, a1, a2, a3, cBi[19], t);

    pass_w2(bufB, t, a0, a1, a2, a3);
    __syncthreads();                     // bar2 (cBi reads below were written
                                         // pre-bar0; Plo dead after this)
    pass_r2(bufB, t, a0, a1, a2, a3);

    // phase3 @H0: B flat 11,12,13
    lrot4<2>(a0, a1, a2, a3, cBi[11], t);
    lrot4<4>(a0, a1, a2, a3, cBi[12], t);
    lrot4<8>(a0, a1, a2, a3, cBi[13], t);

    float4* gp2 = (float4*)(psi + ga);
    gp2[0] = make_float4(a0.x, a0.y, a1.x, a1.y);
    gp2[1] = make_float4(a2.x, a2.y, a3.x, a3.y);
}

// ---------------- mega-kernel: 8 sweeps, 7 two-level grid barriers ----------
__global__ __launch_bounds__(1024)
void mega_kernel(float2* __restrict__ psi, const float* __restrict__ th,
                 const float* __restrict__ ph, float2* __restrict__ cw,
                 float* __restrict__ outP, unsigned* __restrict__ bar) {
    __shared__ __align__(16) float2 bufA[4096];
    __shared__ __align__(16) float2 bufB[4096];
    __shared__ float2 Plo[1024];
    __shared__ float2 Phh[512];
    const int t = threadIdx.x, blk = blockIdx.x;

    sweep_init(psi, th, ph, cw, bufA, bufB, Plo, Phh, t, blk);
    gbar_arrive(bar, 1); build_D(Plo, Phh, ph + 19, t);  gbar_wait(bar, 1);
    sweep_low<false>(psi, cw + 20,  cw + 40,  nullptr, bufA, bufB, Plo, Phh, t, blk);
    gbar_arrive(bar, 2); build_D(Plo, Phh, ph + 38, t);  gbar_wait(bar, 2);
    sweep_hi        (psi, cw + 40,  cw + 60,           bufA, bufB, Plo, Phh, t, blk);
    gbar_arrive(bar, 3); build_D(Plo, Phh, ph + 57, t);  gbar_wait(bar, 3);
    sweep_low<false>(psi, cw + 60,  cw + 80,  nullptr, bufA, bufB, Plo, Phh, t, blk);
    gbar_arrive(bar, 4); build_D(Plo, Phh, ph + 76, t);  gbar_wait(bar, 4);
    sweep_hi        (psi, cw + 80,  cw + 100,          bufA, bufB, Plo, Phh, t, blk);
    gbar_arrive(bar, 5); build_D(Plo, Phh, ph + 95, t);  gbar_wait(bar, 5);
    sweep_low<false>(psi, cw + 100, cw + 120, nullptr, bufA, bufB, Plo, Phh, t, blk);
    gbar_arrive(bar, 6); build_D(Plo, Phh, ph + 114, t); gbar_wait(bar, 6);
    sweep_hi        (psi, cw + 120, cw + 140,          bufA, bufB, Plo, Phh, t, blk);
    gbar_arrive(bar, 7);                                 gbar_wait(bar, 7);
    sweep_low<true> (psi, cw + 140, cw + 140, outP,    bufA, bufB, Plo, Phh, t, blk);
}

extern "C" void kernel_launch(void* const* d_in, const int* in_sizes, int n_in,
                              void* d_out, int out_size, void* d_ws, size_t ws_size,
                              hipStream_t stream) {
    (void)in_sizes; (void)n_in; (void)out_size; (void)ws_size;
    const float* th = (const float*)d_in[0];   // (8,20)
    const float* ph = (const float*)d_in[1];   // (8,19)
    float2* psi = (float2*)d_ws;               // 2^20 complex64 = 8 MB
    float2* cw  = (float2*)((char*)d_ws + (8u << 20));            // coeff dump
    unsigned* bar = (unsigned*)((char*)d_ws + (8u << 20) + 4096); // barrier, 4KB
    float* out = (float*)d_out;

    (void)hipMemsetAsync(bar, 0, 4096, stream);
    mega_kernel<<<NBLK, 1024, 0, stream>>>(psi, th, ph, cw, out, bar);
}

// Round 6
// 89.763 us; speedup vs baseline: 2.8261x; 2.0365x over previous
//
#include <hip/hip_runtime.h>

// 20-qubit statevector, 8 layers {Ry x20, CZ chain, Rzz chain}, out = |psi|^2.
// R6 = R2 (8 separate kernels, best verified: 94.6 us) + hi-layout chunk
// pairing: cid = ((blk&7)<<5)|(blk>>3) so the two 64B half-lines of every
// 128B psi cache line are owned by blocks on the SAME XCD (blk%8 round-robin)
// -> each L2 fetches the line once, writes merge to full-line dirties.
// Butterfly structure: 4 amps/thread in registers; rotations on reg bits
// (free) and lane bits (DPP, VALU pipe); wave bits moved by TWO XOR-swizzled
// LDS transpose passes (2 barriers/kernel).
// Layouts (tile index n[11:0], thread t[9:0], amp j[1:0]):
//  L0: reg={n1,n0} lanes={n7..n2} wave={n11..n8}   (global-coalesced order)
//  Q : reg={n7,n6} lanes={n5,n4 parked | n11..n8}  wave={n3..n0}
// LOW kernel: A=flat0..10, D, B=flat0..11 ; HI: A=flat12..19, D, B=flat11..19
// DPP semantics: row_shr:N = from lane i-N, row_shl:N = from lane i+N.

#define QN 20

__device__ __forceinline__ float2 cmulf(float2 a, float2 b) {
    return make_float2(a.x * b.x - a.y * b.y, a.x * b.y + a.y * b.x);
}

// ---- rotation on register bits: w = (cos, sin) -----------------------------
__device__ __forceinline__ void rot2c(float2& x0, float2& x1, float2 w) {
    float2 t0 = make_float2(w.x * x0.x - w.y * x1.x, w.x * x0.y - w.y * x1.y);
    float2 t1 = make_float2(w.y * x0.x + w.x * x1.x, w.y * x0.y + w.x * x1.y);
    x0 = t0; x1 = t1;
}
__device__ __forceinline__ void rot4c(float2& a0, float2& a1, float2& a2, float2& a3,
                                      float2 wa, float2 wb) {
    rot2c(a0, a1, wa); rot2c(a2, a3, wa);
    rot2c(a0, a2, wb); rot2c(a1, a3, wb);
}

// ---- DPP cross-lane partner fetch (xor distance X in {1,2,4,8}) ------------
template<int X>
__device__ __forceinline__ float2 xpart(float2 v, int t) {
    int sx = __float_as_int(v.x), sy = __float_as_int(v.y);
    if constexpr (X == 4) {
        // row_shr:4 (0x114): lane i <- i-4 (valid for t&4=1); row_shl:4
        // (0x104): lane i <- i+4 (valid for t&4=0); select by side.
        int ax = __builtin_amdgcn_update_dpp(sx, sx, 0x114, 0xF, 0xF, false);
        int ay = __builtin_amdgcn_update_dpp(sy, sy, 0x114, 0xF, 0xF, false);
        int bx = __builtin_amdgcn_update_dpp(sx, sx, 0x104, 0xF, 0xF, false);
        int by = __builtin_amdgcn_update_dpp(sy, sy, 0x104, 0xF, 0xF, false);
        bool hi = (t & 4) != 0;
        return make_float2(__int_as_float(hi ? ax : bx), __int_as_float(hi ? ay : by));
    } else {
        // xor1: quad_perm[1,0,3,2]=0xB1; xor2: quad_perm[2,3,0,1]=0x4E;
        // xor8: row_ror:8=0x128 ((i+8)%16 == i^8 within a 16-row)
        constexpr int ctrl = (X == 1) ? 0xB1 : (X == 2) ? 0x4E : 0x128;
        return make_float2(
            __int_as_float(__builtin_amdgcn_update_dpp(sx, sx, ctrl, 0xF, 0xF, false)),
            __int_as_float(__builtin_amdgcn_update_dpp(sy, sy, ctrl, 0xF, 0xF, false)));
    }
}

// Ry on a lane bit: own' = c*own + (side? +s : -s)*partner
template<int X>
__device__ __forceinline__ void lrot4(float2& a0, float2& a1, float2& a2, float2& a3,
                                      float2 w, int t) {
    float ss = (t & X) ? w.y : -w.y;
    float2 p0 = xpart<X>(a0, t), p1 = xpart<X>(a1, t),
           p2 = xpart<X>(a2, t), p3 = xpart<X>(a3, t);
    a0 = make_float2(fmaf(ss, p0.x, w.x * a0.x), fmaf(ss, p0.y, w.x * a0.y));
    a1 = make_float2(fmaf(ss, p1.x, w.x * a1.x), fmaf(ss, p1.y, w.x * a1.y));
    a2 = make_float2(fmaf(ss, p2.x, w.x * a2.x), fmaf(ss, p2.y, w.x * a2.y));
    a3 = make_float2(fmaf(ss, p3.x, w.x * a3.x), fmaf(ss, p3.y, w.x * a3.y));
}

// ---- diagonal (CZ chain + Rzz chain) phase ---------------------------------
__device__ __forceinline__ float2 dphase(int x, const float2* Plo, const float2* Phh) {
    int y = (x ^ (x >> 1)) & 0x7FFFF;
    float2 p = cmulf(Plo[y & 1023], Phh[y >> 10]);
    int sgn = (__popc(x & (x >> 1) & 0x7FFFF) & 1) << 31;
    p.x = __int_as_float(__float_as_int(p.x) ^ sgn);
    p.y = __int_as_float(__float_as_int(p.y) ^ sgn);
    return p;
}

__device__ __forceinline__ void build_D(float2* Plo, float2* Phh,
                                        const float* __restrict__ ph, int t) {
    float pw[19];
    #pragma unroll
    for (int j = 0; j < 19; ++j) pw[j] = ph[18 - j];   // uniform loads
    float S = 0.f;
    #pragma unroll
    for (int j = 0; j < 19; ++j) S += pw[j];
    float ang = 0.f;
    #pragma unroll
    for (int j = 0; j < 10; ++j) if ((t >> j) & 1) ang += pw[j];
    Plo[t] = make_float2(cosf(ang), sinf(ang));
    if (t < 512) {
        float a2 = -0.5f * S;
        #pragma unroll
        for (int j = 0; j < 9; ++j) if ((t >> j) & 1) a2 += pw[10 + j];
        Phh[t] = make_float2(cosf(a2), sinf(a2));
    }
}

// ---- LDS transpose passes (bank-floor XOR swizzles) ------------------------
__device__ __forceinline__ void pass_w1(float2* buf, int t,
                                        float2 a0, float2 a1, float2 a2, float2 a3) {
    int mb = ((t >> 4) & 3) | (((t >> 6) & 0xF) << 2) |
             (((t >> 2) & 3) << 6) | ((t & 3) << 10);
    int pb = mb ^ ((t & 3) << 2) ^ (((t >> 2) & 3) << 4);
    buf[pb] = a0; buf[pb | 256] = a1; buf[pb | 512] = a2; buf[pb | 768] = a3;
}
__device__ __forceinline__ void pass_r1(const float2* buf, int t,
                                        float2& a0, float2& a1, float2& a2, float2& a3) {
    int rb = (4 * t) ^ (((t >> 8) & 3) << 2) ^ (((t >> 4) & 3) << 4);
    const float4* b4 = (const float4*)(buf + rb);
    float4 u = b4[0], w = b4[1];
    a0 = make_float2(u.x, u.y); a1 = make_float2(u.z, u.w);
    a2 = make_float2(w.x, w.y); a3 = make_float2(w.z, w.w);
}
__device__ __forceinline__ int q_nb(int t) {
    return ((t >> 6) & 0xF) | (((t >> 4) & 3) << 4) | ((t & 0xF) << 8);
}
__device__ __forceinline__ void pass_w2(float2* buf, int t,
                                        float2 a0, float2 a1, float2 a2, float2 a3) {
    int nb = q_nb(t);
    int qb = nb ^ (t & 3) ^ (((t >> 2) & 3) << 2);
    buf[qb] = a0; buf[qb ^ 0x50] = a1; buf[qb ^ 0xA0] = a2; buf[qb ^ 0xF0] = a3;
}
__device__ __forceinline__ void pass_r2(const float2* buf, int t,
                                        float2& a0, float2& a1, float2& a2, float2& a3) {
    int rb = (4 * t) ^ (((t >> 8) & 3) << 2) ^ (((t >> 4) & 3) << 4);
    const float4* b4 = (const float4*)(buf + rb);
    float4 u = b4[0], w = b4[1];
    float2 r0 = make_float2(u.x, u.y), r1 = make_float2(u.z, u.w),
           r2 = make_float2(w.x, w.y), r3 = make_float2(w.z, w.w);
    int k = (t >> 6) & 3;                       // wave-uniform in-quad xor
    if (k & 1) { float2 x = r0; r0 = r1; r1 = x; x = r2; r2 = r3; r3 = x; }
    if (k & 2) { float2 x = r0; r0 = r2; r2 = x; x = r1; r1 = r3; r3 = x; }
    a0 = r0; a1 = r1; a2 = r2; a3 = r3;
}

__device__ __forceinline__ int hi_x(int n, int cid) {
    return ((n >> 3) << 11) | (cid << 3) | (n & 7);
}

// ---------------- LOW kernel: tile = contiguous 4096 amps -------------------
template<bool LAST>
__global__ __launch_bounds__(1024)
void low_kernel(float2* __restrict__ psi, const float2* __restrict__ cA,
                const float2* __restrict__ cB, const float* __restrict__ ph,
                float* __restrict__ outP) {
    __shared__ __align__(16) float2 bufA[4096];
    __shared__ __align__(16) float2 bufB[4096];
    __shared__ float2 Plo[1024];
    __shared__ float2 Phh[512];
    const int t = threadIdx.x, blk = blockIdx.x;

    const float4* gp = (const float4*)(psi + (blk << 12));
    float4 v0 = gp[2 * t], v1 = gp[2 * t + 1];

    if (!LAST) build_D(Plo, Phh, ph, t);

    float2 a0 = make_float2(v0.x, v0.y), a1 = make_float2(v0.z, v0.w),
           a2 = make_float2(v1.x, v1.y), a3 = make_float2(v1.z, v1.w);

    // phase1 @L0: A flat 0..5
    rot4c(a0, a1, a2, a3, cA[0], cA[1]);
    lrot4<1>(a0, a1, a2, a3, cA[2], t);
    lrot4<2>(a0, a1, a2, a3, cA[3], t);
    lrot4<4>(a0, a1, a2, a3, cA[4], t);
    lrot4<8>(a0, a1, a2, a3, cA[5], t);

    pass_w1(bufA, t, a0, a1, a2, a3);
    __syncthreads();                     // bar1 (also covers Plo/Phh writes)
    pass_r1(bufA, t, a0, a1, a2, a3);

    // phase2 @Q: A flat 6..10
    rot4c(a0, a1, a2, a3, cA[6], cA[7]);
    lrot4<1>(a0, a1, a2, a3, cA[8], t);
    lrot4<2>(a0, a1, a2, a3, cA[9], t);
    lrot4<4>(a0, a1, a2, a3, cA[10], t);

    int nb = q_nb(t);
    if (LAST) {
        // |amp|^2 -> float buffer -> coalesced float4 out (D_7 elided)
        float* bf = (float*)bufB;
        int qb = nb ^ (t & 3) ^ (((t >> 2) & 3) << 2);
        bf[qb]        = a0.x * a0.x + a0.y * a0.y;
        bf[qb ^ 0x50] = a1.x * a1.x + a1.y * a1.y;
        bf[qb ^ 0xA0] = a2.x * a2.x + a2.y * a2.y;
        bf[qb ^ 0xF0] = a3.x * a3.x + a3.y * a3.y;
        __syncthreads();
        int rb = (4 * t) ^ (((t >> 8) & 3) << 2) ^ (((t >> 4) & 3) << 4);
        float4 u = *(const float4*)(bf + rb);
        int k = (t >> 6) & 3;
        if (k & 1) { float x = u.x; u.x = u.y; u.y = x; x = u.z; u.z = u.w; u.w = x; }
        if (k & 2) { float x = u.x; u.x = u.z; u.z = x; x = u.y; u.y = u.w; u.w = x; }
        *(float4*)(outP + (blk << 12) + 4 * t) = u;
    } else {
        int xb = blk << 12;
        a0 = cmulf(a0, dphase(xb | nb,        Plo, Phh));
        a1 = cmulf(a1, dphase(xb | nb | 0x40, Plo, Phh));
        a2 = cmulf(a2, dphase(xb | nb | 0x80, Plo, Phh));
        a3 = cmulf(a3, dphase(xb | nb | 0xC0, Plo, Phh));
        // B flat 6..11 (still in Q)
        rot4c(a0, a1, a2, a3, cB[6], cB[7]);
        lrot4<1>(a0, a1, a2, a3, cB[8], t);
        lrot4<2>(a0, a1, a2, a3, cB[9], t);
        lrot4<4>(a0, a1, a2, a3, cB[10], t);
        lrot4<8>(a0, a1, a2, a3, cB[11], t);

        pass_w2(bufB, t, a0, a1, a2, a3);
        __syncthreads();                 // bar2
        pass_r2(bufB, t, a0, a1, a2, a3);

        // phase3 @L0: B flat 0..5
        lrot4<1>(a0, a1, a2, a3, cB[2], t);
        lrot4<2>(a0, a1, a2, a3, cB[3], t);
        lrot4<4>(a0, a1, a2, a3, cB[4], t);
        lrot4<8>(a0, a1, a2, a3, cB[5], t);
        rot4c(a0, a1, a2, a3, cB[0], cB[1]);
        float4* op = (float4*)(psi + (blk << 12));
        op[2 * t]     = make_float4(a0.x, a0.y, a1.x, a1.y);
        op[2 * t + 1] = make_float4(a2.x, a2.y, a3.x, a3.y);
    }
}

// ---------------- HI kernel: n3..n11 = flat 11..19, n0..n2 = flat 0..2 ------
// cid pairs half-lines onto one XCD: chunks {2c,2c+1} <-> blocks {8b+a,8b+8+a}.
__global__ __launch_bounds__(1024)
void hi_kernel(float2* __restrict__ psi, const float2* __restrict__ cA,
               const float2* __restrict__ cB, const float* __restrict__ ph) {
    __shared__ __align__(16) float2 bufA[4096];
    __shared__ __align__(16) float2 bufB[4096];
    __shared__ float2 Plo[1024];
    __shared__ float2 Phh[512];
    const int t = threadIdx.x, blk = blockIdx.x;
    const int cid = ((blk & 7) << 5) | (blk >> 3);   // bijective chunk remap
    const int ga = ((t >> 1) << 11) | (cid << 3) | ((t & 1) << 2);  // n = 4t+j

    const float4* gp = (const float4*)(psi + ga);
    float4 v0 = gp[0], v1 = gp[1];

    build_D(Plo, Phh, ph, t);

    float2 a0 = make_float2(v0.x, v0.y), a1 = make_float2(v0.z, v0.w),
           a2 = make_float2(v1.x, v1.y), a3 = make_float2(v1.z, v1.w);

    // phase1 @H0: A flat 12,13 (n4,n5)
    lrot4<4>(a0, a1, a2, a3, cA[12], t);
    lrot4<8>(a0, a1, a2, a3, cA[13], t);

    pass_w1(bufA, t, a0, a1, a2, a3);
    __syncthreads();                     // bar1
    pass_r1(bufA, t, a0, a1, a2, a3);

    // phase2 @Q: A flat 14..19 (n6..n11)
    rot4c(a0, a1, a2, a3, cA[14], cA[15]);
    lrot4<1>(a0, a1, a2, a3, cA[16], t);
    lrot4<2>(a0, a1, a2, a3, cA[17], t);
    lrot4<4>(a0, a1, a2, a3, cA[18], t);
    lrot4<8>(a0, a1, a2, a3, cA[19], t);

    int nb = q_nb(t);
    a0 = cmulf(a0, dphase(hi_x(nb,        cid), Plo, Phh));
    a1 = cmulf(a1, dphase(hi_x(nb | 0x40, cid), Plo, Phh));
    a2 = cmulf(a2, dphase(hi_x(nb | 0x80, cid), Plo, Phh));
    a3 = cmulf(a3, dphase(hi_x(nb | 0xC0, cid), Plo, Phh));

    // B flat 14..19 (still in Q)
    rot4c(a0, a1, a2, a3, cB[14], cB[15]);
    lrot4<1>(a0, a1, a2, a3, cB[16], t);
    lrot4<2>(a0, a1, a2, a3, cB[17], t);
    lrot4<4>(a0, a1, a2, a3, cB[18], t);
    lrot4<8>(a0, a1, a2, a3, cB[19], t);

    pass_w2(bufB, t, a0, a1, a2, a3);
    __syncthreads();                     // bar2
    pass_r2(bufB, t, a0, a1, a2, a3);

    // phase3 @H0: B flat 11,12,13 (n3,n4,n5)
    lrot4<2>(a0, a1, a2, a3, cB[11], t);
    lrot4<4>(a0, a1, a2, a3, cB[12], t);
    lrot4<8>(a0, a1, a2, a3, cB[13], t);

    float4* gp2 = (float4*)(psi + ga);
    gp2[0] = make_float4(a0.x, a0.y, a1.x, a1.y);
    gp2[1] = make_float4(a2.x, a2.y, a3.x, a3.y);
}

// ---------------- INIT kernel: synth Ry_0|0>, D_0, B = Ry_1 flat 11..19 -----
// Also dumps cos/sin(theta/2) for all 8 layers to cw for later kernels.
__global__ __launch_bounds__(1024)
void init_kernel(float2* __restrict__ psi, const float* __restrict__ th,
                 const float* __restrict__ ph, float2* __restrict__ cw) {
    __shared__ __align__(16) float2 bufB[4096];
    __shared__ float2 Plo[1024];
    __shared__ float2 Phh[512];
    __shared__ float Alo[1024], Ahi[1024];
    __shared__ float2 cAi[20], cBi[20];
    const int t = threadIdx.x, blk = blockIdx.x;
    const int cid = ((blk & 7) << 5) | (blk >> 3);   // match hi_kernel layout
    const int ga = ((t >> 1) << 11) | (cid << 3) | ((t & 1) << 2);

    if (t < 256) {
        int l = t >> 5, f = t & 31;
        if (f < 20) {
            double a = 0.5 * (double)th[l * 20 + 19 - f];
            float2 w = make_float2((float)cos(a), (float)sin(a));
            cw[l * 20 + f] = w;
            if (l == 0) cAi[f] = w;
            else if (l == 1) cBi[f] = w;
        }
    }
    __syncthreads();                     // bar0: cAi/cBi ready

    build_D(Plo, Phh, ph, t);
    {
        float pl = 1.f, ph2 = 1.f;
        #pragma unroll
        for (int j = 0; j < 10; ++j) {
            pl  *= ((t >> j) & 1) ? cAi[j].y      : cAi[j].x;
            ph2 *= ((t >> j) & 1) ? cAi[10 + j].y : cAi[10 + j].x;
        }
        Alo[t] = pl; Ahi[t] = ph2;
    }
    __syncthreads();                     // bar1: tables ready

    // synth product state directly in Q layout, D_0 fused
    int nb = q_nb(t);
    float2 a0, a1, a2, a3;
    {
        int x0 = hi_x(nb, cid),        x1 = hi_x(nb | 0x40, cid),
            x2 = hi_x(nb | 0x80, cid), x3 = hi_x(nb | 0xC0, cid);
        float m0 = Alo[x0 & 1023] * Ahi[x0 >> 10];
        float m1 = Alo[x1 & 1023] * Ahi[x1 >> 10];
        float m2 = Alo[x2 & 1023] * Ahi[x2 >> 10];
        float m3 = Alo[x3 & 1023] * Ahi[x3 >> 10];
        float2 d0 = dphase(x0, Plo, Phh), d1 = dphase(x1, Plo, Phh),
               d2 = dphase(x2, Plo, Phh), d3 = dphase(x3, Plo, Phh);
        a0 = make_float2(m0 * d0.x, m0 * d0.y);
        a1 = make_float2(m1 * d1.x, m1 * d1.y);
        a2 = make_float2(m2 * d2.x, m2 * d2.y);
        a3 = make_float2(m3 * d3.x, m3 * d3.y);
    }

    // B = Ry_1 flat 14..19 in Q
    rot4c(a0, a1, a2, a3, cBi[14], cBi[15]);
    lrot4<1>(a0, a1, a2, a3, cBi[16], t);
    lrot4<2>(a0, a1, a2, a3, cBi[17], t);
    lrot4<4>(a0, a1, a2, a3, cBi[18], t);
    lrot4<8>(a0, a1, a2, a3, cBi[19], t);

    pass_w2(bufB, t, a0, a1, a2, a3);
    __syncthreads();                     // bar2
    pass_r2(bufB, t, a0, a1, a2, a3);

    // phase3 @H0: B flat 11,12,13
    lrot4<2>(a0, a1, a2, a3, cBi[11], t);
    lrot4<4>(a0, a1, a2, a3, cBi[12], t);
    lrot4<8>(a0, a1, a2, a3, cBi[13], t);

    float4* gp2 = (float4*)(psi + ga);
    gp2[0] = make_float4(a0.x, a0.y, a1.x, a1.y);
    gp2[1] = make_float4(a2.x, a2.y, a3.x, a3.y);
}

extern "C" void kernel_launch(void* const* d_in, const int* in_sizes, int n_in,
                              void* d_out, int out_size, void* d_ws, size_t ws_size,
                              hipStream_t stream) {
    (void)in_sizes; (void)n_in; (void)out_size; (void)ws_size;
    const float* th = (const float*)d_in[0];   // (8,20)
    const float* ph = (const float*)d_in[1];   // (8,19)
    float2* psi = (float2*)d_ws;               // 2^20 complex64 = 8 MB
    float2* cw  = (float2*)((char*)d_ws + (8u << 20));  // 8*20 float2 coeffs
    float* out = (float*)d_out;

    init_kernel      <<<256, 1024, 0, stream>>>(psi, th, ph, cw);
    low_kernel<false><<<256, 1024, 0, stream>>>(psi, cw + 1 * 20, cw + 2 * 20, ph +  19, nullptr);
    hi_kernel        <<<256, 1024, 0, stream>>>(psi, cw + 2 * 20, cw + 3 * 20, ph +  38);
    low_kernel<false><<<256, 1024, 0, stream>>>(psi, cw + 3 * 20, cw + 4 * 20, ph +  57, nullptr);
    hi_kernel        <<<256, 1024, 0, stream>>>(psi, cw + 4 * 20, cw + 5 * 20, ph +  76);
    low_kernel<false><<<256, 1024, 0, stream>>>(psi, cw + 5 * 20, cw + 6 * 20, ph +  95, nullptr);
    hi_kernel        <<<256, 1024, 0, stream>>>(psi, cw + 6 * 20, cw + 7 * 20, ph + 114);
    low_kernel<true ><<<256, 1024, 0, stream>>>(psi, cw + 7 * 20, cw + 7 * 20, ph + 133, out);
}

// Round 7
// 84.527 us; speedup vs baseline: 3.0012x; 1.0619x over previous
//
#include <hip/hip_runtime.h>

// 20-qubit statevector, 8 layers {Ry x20, CZ chain, Rzz chain}, out = |psi|^2.
// R7: 2048-amp tiles, 512 blocks x 512 threads => 2 blocks/CU co-resident
// (LDS 44 KB/block): two independent barrier groups per CU overlap each
// other's load/barrier/store stalls (R5 showed sweeps are lockstep-stall
// bound: ~2us VALU + ~2us mem inside ~10.5us).
// Schedule (1 pass/layer, rebalanced for 11-bit tiles):
//  LOW resident flat 0..10:  A=Ry_l(0..10), D_l, B=Ry_{l+1}(0..10)
//  HI  resident {0,1}u{11..19}: A=Ry_l(11..19), D_l, B=Ry_{l+1}(11..19)
// Tile n[10:0], thread t[8:0], amp j[1:0]:
//  L0: reg={n1,n0} lanes={n7..n2} wave={n10..n8}  (global-coalesced)
//  Q : reg={n7,n6} lanes={n8,n9,n10,n3,n4,n5} wave={n2,n1,n0}
// Transpose-1 storage m(n)={n6,n7,n8,n9,n10,n3,n4,n5,n0,n1,n2}, swizzle
// p=m^(m[7:5]<<2); Transpose-2 storage q=n^(n[10:8]) (bits 2..0).
// HI global map: x = j[1:0] | cid<<2 | (m>>2)<<11 ; cid=((blk>>7)&3)|((blk&127)<<2)
// so the 4 blocks sharing each 128B line sit on one XCD (blk%8 equal).
// DPP semantics: row_shr:N = from lane i-N, row_shl:N = from lane i+N.

#define QN 20

__device__ __forceinline__ float2 cmulf(float2 a, float2 b) {
    return make_float2(a.x * b.x - a.y * b.y, a.x * b.y + a.y * b.x);
}

// ---- rotation on register bits: w = (cos, sin) -----------------------------
__device__ __forceinline__ void rot2c(float2& x0, float2& x1, float2 w) {
    float2 t0 = make_float2(w.x * x0.x - w.y * x1.x, w.x * x0.y - w.y * x1.y);
    float2 t1 = make_float2(w.y * x0.x + w.x * x1.x, w.y * x0.y + w.x * x1.y);
    x0 = t0; x1 = t1;
}
__device__ __forceinline__ void rot4c(float2& a0, float2& a1, float2& a2, float2& a3,
                                      float2 wa, float2 wb) {
    rot2c(a0, a1, wa); rot2c(a2, a3, wa);
    rot2c(a0, a2, wb); rot2c(a1, a3, wb);
}

// ---- DPP cross-lane partner fetch (xor distance X in {1,2,4,8}) ------------
template<int X>
__device__ __forceinline__ float2 xpart(float2 v, int t) {
    int sx = __float_as_int(v.x), sy = __float_as_int(v.y);
    if constexpr (X == 4) {
        // row_shr:4 (0x114): lane i <- i-4 (t&4=1 side); row_shl:4 (0x104):
        // lane i <- i+4 (t&4=0 side); select by side.
        int ax = __builtin_amdgcn_update_dpp(sx, sx, 0x114, 0xF, 0xF, false);
        int ay = __builtin_amdgcn_update_dpp(sy, sy, 0x114, 0xF, 0xF, false);
        int bx = __builtin_amdgcn_update_dpp(sx, sx, 0x104, 0xF, 0xF, false);
        int by = __builtin_amdgcn_update_dpp(sy, sy, 0x104, 0xF, 0xF, false);
        bool hi = (t & 4) != 0;
        return make_float2(__int_as_float(hi ? ax : bx), __int_as_float(hi ? ay : by));
    } else {
        // xor1: quad_perm[1,0,3,2]=0xB1; xor2: quad_perm[2,3,0,1]=0x4E;
        // xor8: row_ror:8=0x128 ((i+8)%16 == i^8 within a 16-row)
        constexpr int ctrl = (X == 1) ? 0xB1 : (X == 2) ? 0x4E : 0x128;
        return make_float2(
            __int_as_float(__builtin_amdgcn_update_dpp(sx, sx, ctrl, 0xF, 0xF, false)),
            __int_as_float(__builtin_amdgcn_update_dpp(sy, sy, ctrl, 0xF, 0xF, false)));
    }
}

// Ry on a lane bit: own' = c*own + (side? +s : -s)*partner
template<int X>
__device__ __forceinline__ void lrot4(float2& a0, float2& a1, float2& a2, float2& a3,
                                      float2 w, int t) {
    float ss = (t & X) ? w.y : -w.y;
    float2 p0 = xpart<X>(a0, t), p1 = xpart<X>(a1, t),
           p2 = xpart<X>(a2, t), p3 = xpart<X>(a3, t);
    a0 = make_float2(fmaf(ss, p0.x, w.x * a0.x), fmaf(ss, p0.y, w.x * a0.y));
    a1 = make_float2(fmaf(ss, p1.x, w.x * a1.x), fmaf(ss, p1.y, w.x * a1.y));
    a2 = make_float2(fmaf(ss, p2.x, w.x * a2.x), fmaf(ss, p2.y, w.x * a2.y));
    a3 = make_float2(fmaf(ss, p3.x, w.x * a3.x), fmaf(ss, p3.y, w.x * a3.y));
}

// ---- diagonal (CZ chain + Rzz chain) phase ---------------------------------
__device__ __forceinline__ float2 dphase(int x, const float2* Plo, const float2* Phh) {
    int y = (x ^ (x >> 1)) & 0x7FFFF;
    float2 p = cmulf(Plo[y & 1023], Phh[y >> 10]);
    int sgn = (__popc(x & (x >> 1) & 0x7FFFF) & 1) << 31;
    p.x = __int_as_float(__float_as_int(p.x) ^ sgn);
    p.y = __int_as_float(__float_as_int(p.y) ^ sgn);
    return p;
}

// 512 threads: each builds 2 Plo entries + 1 Phh entry.
__device__ __forceinline__ void build_D(float2* Plo, float2* Phh,
                                        const float* __restrict__ ph, int t) {
    float pw[19];
    #pragma unroll
    for (int j = 0; j < 19; ++j) pw[j] = ph[18 - j];   // uniform loads
    float S = 0.f;
    #pragma unroll
    for (int j = 0; j < 19; ++j) S += pw[j];
    #pragma unroll
    for (int k2 = 0; k2 < 2; ++k2) {
        int i = t + (k2 << 9);
        float ang = 0.f;
        #pragma unroll
        for (int j = 0; j < 10; ++j) if ((i >> j) & 1) ang += pw[j];
        Plo[i] = make_float2(cosf(ang), sinf(ang));
    }
    {
        float a2 = -0.5f * S;
        #pragma unroll
        for (int j = 0; j < 9; ++j) if ((t >> j) & 1) a2 += pw[10 + j];
        Phh[t] = make_float2(cosf(a2), sinf(a2));
    }
}

// ---- transpose 1 (L0 -> Q), 2048-amp tile ----------------------------------
// m(n): m[1:0]={n6,n7}? no: m0=n6,m1=n7,m[4:2]={n8,n9,n10},m[7:5]={n3,n4,n5},
// m[9:8]={n0,n1}, m10=n2.  store at p = m ^ (m[7:5]<<2).
__device__ __forceinline__ void pass_w1(float2* buf, int t,
                                        float2 a0, float2 a1, float2 a2, float2 a3) {
    int mb = ((t >> 4) & 3) | (((t >> 6) & 7) << 2) |
             (((t >> 1) & 7) << 5) | ((t & 1) << 10);
    int pb = mb ^ (((t >> 1) & 7) << 2);
    buf[pb] = a0; buf[pb | 0x100] = a1; buf[pb | 0x200] = a2; buf[pb | 0x300] = a3;
}
__device__ __forceinline__ void pass_r1(const float2* buf, int t,
                                        float2& a0, float2& a1, float2& a2, float2& a3) {
    int rb = (4 * t) ^ (((t >> 3) & 7) << 2);
    const float4* b4 = (const float4*)(buf + rb);
    float4 u = b4[0], w = b4[1];
    a0 = make_float2(u.x, u.y); a1 = make_float2(u.z, u.w);
    a2 = make_float2(w.x, w.y); a3 = make_float2(w.z, w.w);
}
// Q thread's tile-index base (j' lands at n[7:6])
__device__ __forceinline__ int q_nb(int t) {
    return ((t >> 6) & 7) | (((t >> 3) & 7) << 3) | ((t & 7) << 8);
}
// ---- transpose 2 (Q -> L0): store at q = n ^ ((n>>8)&7) --------------------
__device__ __forceinline__ void pass_w2(float2* buf, int t,
                                        float2 a0, float2 a1, float2 a2, float2 a3) {
    int q0 = q_nb(t) ^ (t & 7);
    buf[q0] = a0; buf[q0 | 0x40] = a1; buf[q0 | 0x80] = a2; buf[q0 | 0xC0] = a3;
}
__device__ __forceinline__ void pass_r2(const float2* buf, int t,
                                        float2& a0, float2& a1, float2& a2, float2& a3) {
    int rb = (4 * t) ^ (((t >> 8) & 1) << 2);
    const float4* b4 = (const float4*)(buf + rb);
    float4 u = b4[0], w = b4[1];
    float2 r0 = make_float2(u.x, u.y), r1 = make_float2(u.z, u.w),
           r2 = make_float2(w.x, w.y), r3 = make_float2(w.z, w.w);
    int k = (t >> 6) & 3;                       // wave-uniform in-quad xor
    if (k & 1) { float2 x = r0; r0 = r1; r1 = x; x = r2; r2 = r3; r3 = x; }
    if (k & 2) { float2 x = r0; r0 = r2; r2 = x; x = r1; r1 = r3; r3 = x; }
    a0 = r0; a1 = r1; a2 = r2; a3 = r3;
}

// ---------------- LOW kernel: tile = contiguous 2048 amps -------------------
template<bool LAST>
__global__ __launch_bounds__(512)
void low_kernel(float2* __restrict__ psi, const float2* __restrict__ cA,
                const float2* __restrict__ cB, const float* __restrict__ ph,
                float* __restrict__ outP) {
    __shared__ __align__(16) float2 bufA[2048];
    __shared__ __align__(16) float2 bufB[2048];
    __shared__ float2 Plo[1024];
    __shared__ float2 Phh[512];
    const int t = threadIdx.x, blk = blockIdx.x;

    const float4* gp = (const float4*)(psi + (blk << 11));
    float4 v0 = gp[2 * t], v1 = gp[2 * t + 1];

    if (!LAST) build_D(Plo, Phh, ph, t);

    float2 a0 = make_float2(v0.x, v0.y), a1 = make_float2(v0.z, v0.w),
           a2 = make_float2(v1.x, v1.y), a3 = make_float2(v1.z, v1.w);

    // phase1 @L0: A flat 0..5
    rot4c(a0, a1, a2, a3, cA[0], cA[1]);
    lrot4<1>(a0, a1, a2, a3, cA[2], t);
    lrot4<2>(a0, a1, a2, a3, cA[3], t);
    lrot4<4>(a0, a1, a2, a3, cA[4], t);
    lrot4<8>(a0, a1, a2, a3, cA[5], t);

    pass_w1(bufA, t, a0, a1, a2, a3);
    __syncthreads();                     // bar1 (covers Plo/Phh too)
    pass_r1(bufA, t, a0, a1, a2, a3);

    // phase2 @Q: A flat 6..10
    rot4c(a0, a1, a2, a3, cA[6], cA[7]);
    lrot4<1>(a0, a1, a2, a3, cA[8], t);
    lrot4<2>(a0, a1, a2, a3, cA[9], t);
    lrot4<4>(a0, a1, a2, a3, cA[10], t);

    int nb = q_nb(t);
    if (LAST) {
        // |amp|^2 -> float transpose-2 -> coalesced float4 out (D_7 elided)
        float* bf = (float*)bufB;
        int q0 = nb ^ (t & 7);
        bf[q0]        = a0.x * a0.x + a0.y * a0.y;
        bf[q0 | 0x40] = a1.x * a1.x + a1.y * a1.y;
        bf[q0 | 0x80] = a2.x * a2.x + a2.y * a2.y;
        bf[q0 | 0xC0] = a3.x * a3.x + a3.y * a3.y;
        __syncthreads();
        int rbf = (4 * t) ^ (((t >> 8) & 1) << 2);
        float4 u = *(const float4*)(bf + rbf);
        int k = (t >> 6) & 3;
        if (k & 1) { float x = u.x; u.x = u.y; u.y = x; x = u.z; u.z = u.w; u.w = x; }
        if (k & 2) { float x = u.x; u.x = u.z; u.z = x; x = u.y; u.y = u.w; u.w = x; }
        *(float4*)(outP + (blk << 11) + 4 * t) = u;
    } else {
        int xb = blk << 11;
        a0 = cmulf(a0, dphase(xb | nb,            Plo, Phh));
        a1 = cmulf(a1, dphase(xb | nb | (1 << 6), Plo, Phh));
        a2 = cmulf(a2, dphase(xb | nb | (2 << 6), Plo, Phh));
        a3 = cmulf(a3, dphase(xb | nb | (3 << 6), Plo, Phh));
        // B flat 6..10 (still in Q)
        rot4c(a0, a1, a2, a3, cB[6], cB[7]);
        lrot4<1>(a0, a1, a2, a3, cB[8], t);
        lrot4<2>(a0, a1, a2, a3, cB[9], t);
        lrot4<4>(a0, a1, a2, a3, cB[10], t);

        pass_w2(bufB, t, a0, a1, a2, a3);
        __syncthreads();                 // bar2
        pass_r2(bufB, t, a0, a1, a2, a3);

        // phase3 @L0: B flat 0..5
        lrot4<1>(a0, a1, a2, a3, cB[2], t);
        lrot4<2>(a0, a1, a2, a3, cB[3], t);
        lrot4<4>(a0, a1, a2, a3, cB[4], t);
        lrot4<8>(a0, a1, a2, a3, cB[5], t);
        rot4c(a0, a1, a2, a3, cB[0], cB[1]);
        float4* op = (float4*)(psi + (blk << 11));
        op[2 * t]     = make_float4(a0.x, a0.y, a1.x, a1.y);
        op[2 * t + 1] = make_float4(a2.x, a2.y, a3.x, a3.y);
    }
}

// ---------------- HI kernel: tile bits m = {flat0,flat1, flat11..19} --------
__global__ __launch_bounds__(512)
void hi_kernel(float2* __restrict__ psi, const float2* __restrict__ cA,
               const float2* __restrict__ cB, const float* __restrict__ ph) {
    __shared__ __align__(16) float2 bufA[2048];
    __shared__ __align__(16) float2 bufB[2048];
    __shared__ float2 Plo[1024];
    __shared__ float2 Phh[512];
    const int t = threadIdx.x, blk = blockIdx.x;
    const int cid = ((blk >> 7) & 3) | ((blk & 0x7F) << 2);  // line-mates co-XCD
    const int ga = (cid << 2) | ((t & 63) << 11) | (((t >> 6) & 7) << 17);

    const float4* gp = (const float4*)(psi + ga);
    float4 v0 = gp[0], v1 = gp[1];

    build_D(Plo, Phh, ph, t);

    float2 a0 = make_float2(v0.x, v0.y), a1 = make_float2(v0.z, v0.w),
           a2 = make_float2(v1.x, v1.y), a3 = make_float2(v1.z, v1.w);

    // phase1 @H0: A flat 11..14 (m2..m5 at lanes x1,x2,x4,x8)
    lrot4<1>(a0, a1, a2, a3, cA[11], t);
    lrot4<2>(a0, a1, a2, a3, cA[12], t);
    lrot4<4>(a0, a1, a2, a3, cA[13], t);
    lrot4<8>(a0, a1, a2, a3, cA[14], t);

    pass_w1(bufA, t, a0, a1, a2, a3);
    __syncthreads();                     // bar1
    pass_r1(bufA, t, a0, a1, a2, a3);

    // phase2 @Q: A flat 15..19 (m6,m7 reg; m8,m9,m10 lanes x1,x2,x4)
    rot4c(a0, a1, a2, a3, cA[15], cA[16]);
    lrot4<1>(a0, a1, a2, a3, cA[17], t);
    lrot4<2>(a0, a1, a2, a3, cA[18], t);
    lrot4<4>(a0, a1, a2, a3, cA[19], t);

    int mb = q_nb(t);
    int xbase = (mb & 3) | (cid << 2) | ((mb >> 2) << 11);
    a0 = cmulf(a0, dphase(xbase,             Plo, Phh));
    a1 = cmulf(a1, dphase(xbase | (1 << 15), Plo, Phh));
    a2 = cmulf(a2, dphase(xbase | (2 << 15), Plo, Phh));
    a3 = cmulf(a3, dphase(xbase | (3 << 15), Plo, Phh));

    // B flat 15..19 (still in Q)
    rot4c(a0, a1, a2, a3, cB[15], cB[16]);
    lrot4<1>(a0, a1, a2, a3, cB[17], t);
    lrot4<2>(a0, a1, a2, a3, cB[18], t);
    lrot4<4>(a0, a1, a2, a3, cB[19], t);

    pass_w2(bufB, t, a0, a1, a2, a3);
    __syncthreads();                     // bar2
    pass_r2(bufB, t, a0, a1, a2, a3);

    // phase3 @H0: B flat 11..14
    lrot4<1>(a0, a1, a2, a3, cB[11], t);
    lrot4<2>(a0, a1, a2, a3, cB[12], t);
    lrot4<4>(a0, a1, a2, a3, cB[13], t);
    lrot4<8>(a0, a1, a2, a3, cB[14], t);

    float4* gp2 = (float4*)(psi + ga);
    gp2[0] = make_float4(a0.x, a0.y, a1.x, a1.y);
    gp2[1] = make_float4(a2.x, a2.y, a3.x, a3.y);
}

// ---------------- INIT kernel: synth Ry_0|0>, D_0, B = Ry_1(11..19) ---------
// Also dumps cos/sin(theta/2) for all 8 layers to cw for later kernels.
__global__ __launch_bounds__(512)
void init_kernel(float2* __restrict__ psi, const float* __restrict__ th,
                 const float* __restrict__ ph, float2* __restrict__ cw) {
    __shared__ __align__(16) float2 bufA[2048];   // holds Alo/Ahi/cAi/cBi
    __shared__ __align__(16) float2 bufB[2048];
    __shared__ float2 Plo[1024];
    __shared__ float2 Phh[512];
    float* Alo = (float*)bufA;           // floats [0..1023]
    float* Ahi = Alo + 1024;             // floats [1024..2047]
    float2* cAi = bufA + 1024;           // float2 [1024..1043]
    float2* cBi = bufA + 1056;           // float2 [1056..1075]
    const int t = threadIdx.x, blk = blockIdx.x;
    const int cid = ((blk >> 7) & 3) | ((blk & 0x7F) << 2);
    const int ga = (cid << 2) | ((t & 63) << 11) | (((t >> 6) & 7) << 17);

    if (t < 256) {
        int l = t >> 5, f = t & 31;
        if (f < 20) {
            double a = 0.5 * (double)th[l * 20 + 19 - f];
            float2 w = make_float2((float)cos(a), (float)sin(a));
            cw[l * 20 + f] = w;
            if (l == 0) cAi[f] = w;
            else if (l == 1) cBi[f] = w;
        }
    }
    __syncthreads();                     // bar0: cAi/cBi ready

    build_D(Plo, Phh, ph, t);
    #pragma unroll
    for (int k2 = 0; k2 < 2; ++k2) {
        int i = t + (k2 << 9);
        float pl = 1.f, ph2 = 1.f;
        #pragma unroll
        for (int j = 0; j < 10; ++j) {
            pl  *= ((i >> j) & 1) ? cAi[j].y      : cAi[j].x;
            ph2 *= ((i >> j) & 1) ? cAi[10 + j].y : cAi[10 + j].x;
        }
        Alo[i] = pl; Ahi[i] = ph2;
    }
    __syncthreads();                     // bar1: tables ready

    // synth product state directly in Q layout, D_0 fused
    int mb = q_nb(t);
    int xbase = (mb & 3) | (cid << 2) | ((mb >> 2) << 11);
    float2 a0, a1, a2, a3;
    {
        int x0 = xbase,             x1 = xbase | (1 << 15),
            x2 = xbase | (2 << 15), x3 = xbase | (3 << 15);
        float m0 = Alo[x0 & 1023] * Ahi[x0 >> 10];
        float m1 = Alo[x1 & 1023] * Ahi[x1 >> 10];
        float m2 = Alo[x2 & 1023] * Ahi[x2 >> 10];
        float m3 = Alo[x3 & 1023] * Ahi[x3 >> 10];
        float2 d0 = dphase(x0, Plo, Phh), d1 = dphase(x1, Plo, Phh),
               d2 = dphase(x2, Plo, Phh), d3 = dphase(x3, Plo, Phh);
        a0 = make_float2(m0 * d0.x, m0 * d0.y);
        a1 = make_float2(m1 * d1.x, m1 * d1.y);
        a2 = make_float2(m2 * d2.x, m2 * d2.y);
        a3 = make_float2(m3 * d3.x, m3 * d3.y);
    }

    // B = Ry_1 flat 15..19 in Q
    rot4c(a0, a1, a2, a3, cBi[15], cBi[16]);
    lrot4<1>(a0, a1, a2, a3, cBi[17], t);
    lrot4<2>(a0, a1, a2, a3, cBi[18], t);
    lrot4<4>(a0, a1, a2, a3, cBi[19], t);

    pass_w2(bufB, t, a0, a1, a2, a3);
    __syncthreads();                     // bar2 (cBi reads below pre-bar0 data)
    pass_r2(bufB, t, a0, a1, a2, a3);

    // phase3 @H0: B flat 11..14
    lrot4<1>(a0, a1, a2, a3, cBi[11], t);
    lrot4<2>(a0, a1, a2, a3, cBi[12], t);
    lrot4<4>(a0, a1, a2, a3, cBi[13], t);
    lrot4<8>(a0, a1, a2, a3, cBi[14], t);

    float4* gp2 = (float4*)(psi + ga);
    gp2[0] = make_float4(a0.x, a0.y, a1.x, a1.y);
    gp2[1] = make_float4(a2.x, a2.y, a3.x, a3.y);
}

extern "C" void kernel_launch(void* const* d_in, const int* in_sizes, int n_in,
                              void* d_out, int out_size, void* d_ws, size_t ws_size,
                              hipStream_t stream) {
    (void)in_sizes; (void)n_in; (void)out_size; (void)ws_size;
    const float* th = (const float*)d_in[0];   // (8,20)
    const float* ph = (const float*)d_in[1];   // (8,19)
    float2* psi = (float2*)d_ws;               // 2^20 complex64 = 8 MB
    float2* cw  = (float2*)((char*)d_ws + (8u << 20));  // 8*20 float2 coeffs
    float* out = (float*)d_out;

    init_kernel      <<<512, 512, 0, stream>>>(psi, th, ph, cw);
    low_kernel<false><<<512, 512, 0, stream>>>(psi, cw + 1 * 20, cw + 2 * 20, ph +  19, nullptr);
    hi_kernel        <<<512, 512, 0, stream>>>(psi, cw + 2 * 20, cw + 3 * 20, ph +  38);
    low_kernel<false><<<512, 512, 0, stream>>>(psi, cw + 3 * 20, cw + 4 * 20, ph +  57, nullptr);
    hi_kernel        <<<512, 512, 0, stream>>>(psi, cw + 4 * 20, cw + 5 * 20, ph +  76);
    low_kernel<false><<<512, 512, 0, stream>>>(psi, cw + 5 * 20, cw + 6 * 20, ph +  95, nullptr);
    hi_kernel        <<<512, 512, 0, stream>>>(psi, cw + 6 * 20, cw + 7 * 20, ph + 114);
    low_kernel<true ><<<512, 512, 0, stream>>>(psi, cw + 7 * 20, cw + 7 * 20, ph + 133, out);
}

// Round 8
// 84.386 us; speedup vs baseline: 3.0062x; 1.0017x over previous
//
#include <hip/hip_runtime.h>

// 20-qubit statevector, 8 layers {Ry x20, CZ chain, Rzz chain}, out = |psi|^2.
// R8 = R7 (512 blocks x 512 threads, 2 blocks/CU, 2048-amp tiles) + hoisted
// diagonal tables: init_kernel precomputes D-tables for layers 1..6 into
// global ws (6 x 1536 float2, bit-identical order to the old build_D); pass
// kernels replace the per-block sincos table build (~200 VALU/thread) with a
// 12KB coalesced global->LDS copy (L2/L3-hot, shared per XCD).
// Schedule (1 pass/layer):
//  LOW resident flat 0..10:  A=Ry_l(0..10), D_l, B=Ry_{l+1}(0..10)
//  HI  resident {0,1}u{11..19}: A=Ry_l(11..19), D_l, B=Ry_{l+1}(11..19)
// Tile n[10:0], thread t[8:0], amp j[1:0]:
//  L0: reg={n1,n0} lanes={n7..n2} wave={n10..n8}  (global-coalesced)
//  Q : reg={n7,n6} lanes={n8,n9,n10,n3,n4,n5} wave={n2,n1,n0}
// HI global map: x = j[1:0] | cid<<2 | (m>>2)<<11 ; cid=((blk>>7)&3)|((blk&127)<<2)
// so the 4 blocks sharing each 128B line sit on one XCD (blk%8 equal).
// DPP semantics: row_shr:N = from lane i-N, row_shl:N = from lane i+N.

#define QN 20

__device__ __forceinline__ float2 cmulf(float2 a, float2 b) {
    return make_float2(a.x * b.x - a.y * b.y, a.x * b.y + a.y * b.x);
}

// ---- rotation on register bits: w = (cos, sin) -----------------------------
__device__ __forceinline__ void rot2c(float2& x0, float2& x1, float2 w) {
    float2 t0 = make_float2(w.x * x0.x - w.y * x1.x, w.x * x0.y - w.y * x1.y);
    float2 t1 = make_float2(w.y * x0.x + w.x * x1.x, w.y * x0.y + w.x * x1.y);
    x0 = t0; x1 = t1;
}
__device__ __forceinline__ void rot4c(float2& a0, float2& a1, float2& a2, float2& a3,
                                      float2 wa, float2 wb) {
    rot2c(a0, a1, wa); rot2c(a2, a3, wa);
    rot2c(a0, a2, wb); rot2c(a1, a3, wb);
}

// ---- DPP cross-lane partner fetch (xor distance X in {1,2,4,8}) ------------
template<int X>
__device__ __forceinline__ float2 xpart(float2 v, int t) {
    int sx = __float_as_int(v.x), sy = __float_as_int(v.y);
    if constexpr (X == 4) {
        // row_shr:4 (0x114): lane i <- i-4 (t&4=1 side); row_shl:4 (0x104):
        // lane i <- i+4 (t&4=0 side); select by side.
        int ax = __builtin_amdgcn_update_dpp(sx, sx, 0x114, 0xF, 0xF, false);
        int ay = __builtin_amdgcn_update_dpp(sy, sy, 0x114, 0xF, 0xF, false);
        int bx = __builtin_amdgcn_update_dpp(sx, sx, 0x104, 0xF, 0xF, false);
        int by = __builtin_amdgcn_update_dpp(sy, sy, 0x104, 0xF, 0xF, false);
        bool hi = (t & 4) != 0;
        return make_float2(__int_as_float(hi ? ax : bx), __int_as_float(hi ? ay : by));
    } else {
        // xor1: quad_perm[1,0,3,2]=0xB1; xor2: quad_perm[2,3,0,1]=0x4E;
        // xor8: row_ror:8=0x128 ((i+8)%16 == i^8 within a 16-row)
        constexpr int ctrl = (X == 1) ? 0xB1 : (X == 2) ? 0x4E : 0x128;
        return make_float2(
            __int_as_float(__builtin_amdgcn_update_dpp(sx, sx, ctrl, 0xF, 0xF, false)),
            __int_as_float(__builtin_amdgcn_update_dpp(sy, sy, ctrl, 0xF, 0xF, false)));
    }
}

// Ry on a lane bit: own' = c*own + (side? +s : -s)*partner
template<int X>
__device__ __forceinline__ void lrot4(float2& a0, float2& a1, float2& a2, float2& a3,
                                      float2 w, int t) {
    float ss = (t & X) ? w.y : -w.y;
    float2 p0 = xpart<X>(a0, t), p1 = xpart<X>(a1, t),
           p2 = xpart<X>(a2, t), p3 = xpart<X>(a3, t);
    a0 = make_float2(fmaf(ss, p0.x, w.x * a0.x), fmaf(ss, p0.y, w.x * a0.y));
    a1 = make_float2(fmaf(ss, p1.x, w.x * a1.x), fmaf(ss, p1.y, w.x * a1.y));
    a2 = make_float2(fmaf(ss, p2.x, w.x * a2.x), fmaf(ss, p2.y, w.x * a2.y));
    a3 = make_float2(fmaf(ss, p3.x, w.x * a3.x), fmaf(ss, p3.y, w.x * a3.y));
}

// ---- diagonal (CZ chain + Rzz chain) phase ---------------------------------
__device__ __forceinline__ float2 dphase(int x, const float2* Plo, const float2* Phh) {
    int y = (x ^ (x >> 1)) & 0x7FFFF;
    float2 p = cmulf(Plo[y & 1023], Phh[y >> 10]);
    int sgn = (__popc(x & (x >> 1) & 0x7FFFF) & 1) << 31;
    p.x = __int_as_float(__float_as_int(p.x) ^ sgn);
    p.y = __int_as_float(__float_as_int(p.y) ^ sgn);
    return p;
}

// 512 threads: each builds 2 Plo entries + 1 Phh entry (init only, D_0).
__device__ __forceinline__ void build_D(float2* Plo, float2* Phh,
                                        const float* __restrict__ ph, int t) {
    float pw[19];
    #pragma unroll
    for (int j = 0; j < 19; ++j) pw[j] = ph[18 - j];   // uniform loads
    float S = 0.f;
    #pragma unroll
    for (int j = 0; j < 19; ++j) S += pw[j];
    #pragma unroll
    for (int k2 = 0; k2 < 2; ++k2) {
        int i = t + (k2 << 9);
        float ang = 0.f;
        #pragma unroll
        for (int j = 0; j < 10; ++j) if ((i >> j) & 1) ang += pw[j];
        Plo[i] = make_float2(cosf(ang), sinf(ang));
    }
    {
        float a2 = -0.5f * S;
        #pragma unroll
        for (int j = 0; j < 9; ++j) if ((t >> j) & 1) a2 += pw[10 + j];
        Phh[t] = make_float2(cosf(a2), sinf(a2));
    }
}

// Pass kernels: fill Plo/Phh LDS from the precomputed global table (12 KB).
__device__ __forceinline__ void load_D(float2* Plo, float2* Phh,
                                       const float2* __restrict__ tab, int t) {
    float2 p0 = tab[t], p1 = tab[t | 512], p2 = tab[t + 1024];
    Plo[t] = p0; Plo[t | 512] = p1; Phh[t] = p2;
}

// ---- transpose 1 (L0 -> Q), 2048-amp tile ----------------------------------
// m(n): m0=n6,m1=n7,m[4:2]={n8,n9,n10},m[7:5]={n3,n4,n5},m[9:8]={n0,n1},m10=n2.
// store at p = m ^ (m[7:5]<<2).
__device__ __forceinline__ void pass_w1(float2* buf, int t,
                                        float2 a0, float2 a1, float2 a2, float2 a3) {
    int mb = ((t >> 4) & 3) | (((t >> 6) & 7) << 2) |
             (((t >> 1) & 7) << 5) | ((t & 1) << 10);
    int pb = mb ^ (((t >> 1) & 7) << 2);
    buf[pb] = a0; buf[pb | 0x100] = a1; buf[pb | 0x200] = a2; buf[pb | 0x300] = a3;
}
__device__ __forceinline__ void pass_r1(const float2* buf, int t,
                                        float2& a0, float2& a1, float2& a2, float2& a3) {
    int rb = (4 * t) ^ (((t >> 3) & 7) << 2);
    const float4* b4 = (const float4*)(buf + rb);
    float4 u = b4[0], w = b4[1];
    a0 = make_float2(u.x, u.y); a1 = make_float2(u.z, u.w);
    a2 = make_float2(w.x, w.y); a3 = make_float2(w.z, w.w);
}
// Q thread's tile-index base (j' lands at n[7:6])
__device__ __forceinline__ int q_nb(int t) {
    return ((t >> 6) & 7) | (((t >> 3) & 7) << 3) | ((t & 7) << 8);
}
// ---- transpose 2 (Q -> L0): store at q = n ^ ((n>>8)&7) --------------------
__device__ __forceinline__ void pass_w2(float2* buf, int t,
                                        float2 a0, float2 a1, float2 a2, float2 a3) {
    int q0 = q_nb(t) ^ (t & 7);
    buf[q0] = a0; buf[q0 | 0x40] = a1; buf[q0 | 0x80] = a2; buf[q0 | 0xC0] = a3;
}
__device__ __forceinline__ void pass_r2(const float2* buf, int t,
                                        float2& a0, float2& a1, float2& a2, float2& a3) {
    int rb = (4 * t) ^ (((t >> 8) & 1) << 2);
    const float4* b4 = (const float4*)(buf + rb);
    float4 u = b4[0], w = b4[1];
    float2 r0 = make_float2(u.x, u.y), r1 = make_float2(u.z, u.w),
           r2 = make_float2(w.x, w.y), r3 = make_float2(w.z, w.w);
    int k = (t >> 6) & 3;                       // wave-uniform in-quad xor
    if (k & 1) { float2 x = r0; r0 = r1; r1 = x; x = r2; r2 = r3; r3 = x; }
    if (k & 2) { float2 x = r0; r0 = r2; r2 = x; x = r1; r1 = r3; r3 = x; }
    a0 = r0; a1 = r1; a2 = r2; a3 = r3;
}

// ---------------- LOW kernel: tile = contiguous 2048 amps -------------------
template<bool LAST>
__global__ __launch_bounds__(512)
void low_kernel(float2* __restrict__ psi, const float2* __restrict__ cA,
                const float2* __restrict__ cB, const float2* __restrict__ tab,
                float* __restrict__ outP) {
    __shared__ __align__(16) float2 bufA[2048];
    __shared__ __align__(16) float2 bufB[2048];
    __shared__ float2 Plo[1024];
    __shared__ float2 Phh[512];
    const int t = threadIdx.x, blk = blockIdx.x;

    const float4* gp = (const float4*)(psi + (blk << 11));
    float4 v0 = gp[2 * t], v1 = gp[2 * t + 1];

    if (!LAST) load_D(Plo, Phh, tab, t);

    float2 a0 = make_float2(v0.x, v0.y), a1 = make_float2(v0.z, v0.w),
           a2 = make_float2(v1.x, v1.y), a3 = make_float2(v1.z, v1.w);

    // phase1 @L0: A flat 0..5
    rot4c(a0, a1, a2, a3, cA[0], cA[1]);
    lrot4<1>(a0, a1, a2, a3, cA[2], t);
    lrot4<2>(a0, a1, a2, a3, cA[3], t);
    lrot4<4>(a0, a1, a2, a3, cA[4], t);
    lrot4<8>(a0, a1, a2, a3, cA[5], t);

    pass_w1(bufA, t, a0, a1, a2, a3);
    __syncthreads();                     // bar1 (covers Plo/Phh fill too)
    pass_r1(bufA, t, a0, a1, a2, a3);

    // phase2 @Q: A flat 6..10
    rot4c(a0, a1, a2, a3, cA[6], cA[7]);
    lrot4<1>(a0, a1, a2, a3, cA[8], t);
    lrot4<2>(a0, a1, a2, a3, cA[9], t);
    lrot4<4>(a0, a1, a2, a3, cA[10], t);

    int nb = q_nb(t);
    if (LAST) {
        // |amp|^2 -> float transpose-2 -> coalesced float4 out (D_7 elided)
        float* bf = (float*)bufB;
        int q0 = nb ^ (t & 7);
        bf[q0]        = a0.x * a0.x + a0.y * a0.y;
        bf[q0 | 0x40] = a1.x * a1.x + a1.y * a1.y;
        bf[q0 | 0x80] = a2.x * a2.x + a2.y * a2.y;
        bf[q0 | 0xC0] = a3.x * a3.x + a3.y * a3.y;
        __syncthreads();
        int rbf = (4 * t) ^ (((t >> 8) & 1) << 2);
        float4 u = *(const float4*)(bf + rbf);
        int k = (t >> 6) & 3;
        if (k & 1) { float x = u.x; u.x = u.y; u.y = x; x = u.z; u.z = u.w; u.w = x; }
        if (k & 2) { float x = u.x; u.x = u.z; u.z = x; x = u.y; u.y = u.w; u.w = x; }
        *(float4*)(outP + (blk << 11) + 4 * t) = u;
    } else {
        int xb = blk << 11;
        a0 = cmulf(a0, dphase(xb | nb,            Plo, Phh));
        a1 = cmulf(a1, dphase(xb | nb | (1 << 6), Plo, Phh));
        a2 = cmulf(a2, dphase(xb | nb | (2 << 6), Plo, Phh));
        a3 = cmulf(a3, dphase(xb | nb | (3 << 6), Plo, Phh));
        // B flat 6..10 (still in Q)
        rot4c(a0, a1, a2, a3, cB[6], cB[7]);
        lrot4<1>(a0, a1, a2, a3, cB[8], t);
        lrot4<2>(a0, a1, a2, a3, cB[9], t);
        lrot4<4>(a0, a1, a2, a3, cB[10], t);

        pass_w2(bufB, t, a0, a1, a2, a3);
        __syncthreads();                 // bar2
        pass_r2(bufB, t, a0, a1, a2, a3);

        // phase3 @L0: B flat 0..5
        lrot4<1>(a0, a1, a2, a3, cB[2], t);
        lrot4<2>(a0, a1, a2, a3, cB[3], t);
        lrot4<4>(a0, a1, a2, a3, cB[4], t);
        lrot4<8>(a0, a1, a2, a3, cB[5], t);
        rot4c(a0, a1, a2, a3, cB[0], cB[1]);
        float4* op = (float4*)(psi + (blk << 11));
        op[2 * t]     = make_float4(a0.x, a0.y, a1.x, a1.y);
        op[2 * t + 1] = make_float4(a2.x, a2.y, a3.x, a3.y);
    }
}

// ---------------- HI kernel: tile bits m = {flat0,flat1, flat11..19} --------
__global__ __launch_bounds__(512)
void hi_kernel(float2* __restrict__ psi, const float2* __restrict__ cA,
               const float2* __restrict__ cB, const float2* __restrict__ tab) {
    __shared__ __align__(16) float2 bufA[2048];
    __shared__ __align__(16) float2 bufB[2048];
    __shared__ float2 Plo[1024];
    __shared__ float2 Phh[512];
    const int t = threadIdx.x, blk = blockIdx.x;
    const int cid = ((blk >> 7) & 3) | ((blk & 0x7F) << 2);  // line-mates co-XCD
    const int ga = (cid << 2) | ((t & 63) << 11) | (((t >> 6) & 7) << 17);

    const float4* gp = (const float4*)(psi + ga);
    float4 v0 = gp[0], v1 = gp[1];

    load_D(Plo, Phh, tab, t);

    float2 a0 = make_float2(v0.x, v0.y), a1 = make_float2(v0.z, v0.w),
           a2 = make_float2(v1.x, v1.y), a3 = make_float2(v1.z, v1.w);

    // phase1 @H0: A flat 11..14 (m2..m5 at lanes x1,x2,x4,x8)
    lrot4<1>(a0, a1, a2, a3, cA[11], t);
    lrot4<2>(a0, a1, a2, a3, cA[12], t);
    lrot4<4>(a0, a1, a2, a3, cA[13], t);
    lrot4<8>(a0, a1, a2, a3, cA[14], t);

    pass_w1(bufA, t, a0, a1, a2, a3);
    __syncthreads();                     // bar1
    pass_r1(bufA, t, a0, a1, a2, a3);

    // phase2 @Q: A flat 15..19 (m6,m7 reg; m8,m9,m10 lanes x1,x2,x4)
    rot4c(a0, a1, a2, a3, cA[15], cA[16]);
    lrot4<1>(a0, a1, a2, a3, cA[17], t);
    lrot4<2>(a0, a1, a2, a3, cA[18], t);
    lrot4<4>(a0, a1, a2, a3, cA[19], t);

    int mb = q_nb(t);
    int xbase = (mb & 3) | (cid << 2) | ((mb >> 2) << 11);
    a0 = cmulf(a0, dphase(xbase,             Plo, Phh));
    a1 = cmulf(a1, dphase(xbase | (1 << 15), Plo, Phh));
    a2 = cmulf(a2, dphase(xbase | (2 << 15), Plo, Phh));
    a3 = cmulf(a3, dphase(xbase | (3 << 15), Plo, Phh));

    // B flat 15..19 (still in Q)
    rot4c(a0, a1, a2, a3, cB[15], cB[16]);
    lrot4<1>(a0, a1, a2, a3, cB[17], t);
    lrot4<2>(a0, a1, a2, a3, cB[18], t);
    lrot4<4>(a0, a1, a2, a3, cB[19], t);

    pass_w2(bufB, t, a0, a1, a2, a3);
    __syncthreads();                     // bar2
    pass_r2(bufB, t, a0, a1, a2, a3);

    // phase3 @H0: B flat 11..14
    lrot4<1>(a0, a1, a2, a3, cB[11], t);
    lrot4<2>(a0, a1, a2, a3, cB[12], t);
    lrot4<4>(a0, a1, a2, a3, cB[13], t);
    lrot4<8>(a0, a1, a2, a3, cB[14], t);

    float4* gp2 = (float4*)(psi + ga);
    gp2[0] = make_float4(a0.x, a0.y, a1.x, a1.y);
    gp2[1] = make_float4(a2.x, a2.y, a3.x, a3.y);
}

// ---------------- INIT kernel: synth Ry_0|0>, D_0, B = Ry_1(11..19) ---------
// Also dumps cos/sin(theta/2) coeffs AND the D-tables for layers 1..6.
__global__ __launch_bounds__(512)
void init_kernel(float2* __restrict__ psi, const float* __restrict__ th,
                 const float* __restrict__ ph, float2* __restrict__ cw,
                 float2* __restrict__ Dtab) {
    __shared__ __align__(16) float2 bufA[2048];   // holds Alo/Ahi/cAi/cBi
    __shared__ __align__(16) float2 bufB[2048];
    __shared__ float2 Plo[1024];
    __shared__ float2 Phh[512];
    float* Alo = (float*)bufA;           // floats [0..1023]
    float* Ahi = Alo + 1024;             // floats [1024..2047]
    float2* cAi = bufA + 1024;           // float2 [1024..1043]
    float2* cBi = bufA + 1056;           // float2 [1056..1075]
    const int t = threadIdx.x, blk = blockIdx.x;
    const int cid = ((blk >> 7) & 3) | ((blk & 0x7F) << 2);
    const int ga = (cid << 2) | ((t & 63) << 11) | (((t >> 6) & 7) << 17);

    // ---- D-table generation for layers 1..6 (one entry per thread) ----
    {
        int g = blk * 512 + t;
        if (g < 6 * 1536) {
            int l = (g / 1536) + 1;
            int idx = g - (l - 1) * 1536;
            const float* pp = ph + 19 * l;
            float pw[19];
            #pragma unroll
            for (int j = 0; j < 19; ++j) pw[j] = pp[18 - j];
            float2 e;
            if (idx < 1024) {
                float ang = 0.f;
                #pragma unroll
                for (int j = 0; j < 10; ++j) if ((idx >> j) & 1) ang += pw[j];
                e = make_float2(cosf(ang), sinf(ang));
            } else {
                float S = 0.f;
                #pragma unroll
                for (int j = 0; j < 19; ++j) S += pw[j];
                int i2 = idx - 1024;
                float a2 = -0.5f * S;
                #pragma unroll
                for (int j = 0; j < 9; ++j) if ((i2 >> j) & 1) a2 += pw[10 + j];
                e = make_float2(cosf(a2), sinf(a2));
            }
            Dtab[g] = e;
        }
    }

    if (t < 256) {
        int l = t >> 5, f = t & 31;
        if (f < 20) {
            double a = 0.5 * (double)th[l * 20 + 19 - f];
            float2 w = make_float2((float)cos(a), (float)sin(a));
            cw[l * 20 + f] = w;
            if (l == 0) cAi[f] = w;
            else if (l == 1) cBi[f] = w;
        }
    }
    __syncthreads();                     // bar0: cAi/cBi ready

    build_D(Plo, Phh, ph, t);            // D_0 local (used only here)
    #pragma unroll
    for (int k2 = 0; k2 < 2; ++k2) {
        int i = t + (k2 << 9);
        float pl = 1.f, ph2 = 1.f;
        #pragma unroll
        for (int j = 0; j < 10; ++j) {
            pl  *= ((i >> j) & 1) ? cAi[j].y      : cAi[j].x;
            ph2 *= ((i >> j) & 1) ? cAi[10 + j].y : cAi[10 + j].x;
        }
        Alo[i] = pl; Ahi[i] = ph2;
    }
    __syncthreads();                     // bar1: tables ready

    // synth product state directly in Q layout, D_0 fused
    int mb = q_nb(t);
    int xbase = (mb & 3) | (cid << 2) | ((mb >> 2) << 11);
    float2 a0, a1, a2, a3;
    {
        int x0 = xbase,             x1 = xbase | (1 << 15),
            x2 = xbase | (2 << 15), x3 = xbase | (3 << 15);
        float m0 = Alo[x0 & 1023] * Ahi[x0 >> 10];
        float m1 = Alo[x1 & 1023] * Ahi[x1 >> 10];
        float m2 = Alo[x2 & 1023] * Ahi[x2 >> 10];
        float m3 = Alo[x3 & 1023] * Ahi[x3 >> 10];
        float2 d0 = dphase(x0, Plo, Phh), d1 = dphase(x1, Plo, Phh),
               d2 = dphase(x2, Plo, Phh), d3 = dphase(x3, Plo, Phh);
        a0 = make_float2(m0 * d0.x, m0 * d0.y);
        a1 = make_float2(m1 * d1.x, m1 * d1.y);
        a2 = make_float2(m2 * d2.x, m2 * d2.y);
        a3 = make_float2(m3 * d3.x, m3 * d3.y);
    }

    // B = Ry_1 flat 15..19 in Q
    rot4c(a0, a1, a2, a3, cBi[15], cBi[16]);
    lrot4<1>(a0, a1, a2, a3, cBi[17], t);
    lrot4<2>(a0, a1, a2, a3, cBi[18], t);
    lrot4<4>(a0, a1, a2, a3, cBi[19], t);

    pass_w2(bufB, t, a0, a1, a2, a3);
    __syncthreads();                     // bar2 (cBi reads below pre-bar0 data)
    pass_r2(bufB, t, a0, a1, a2, a3);

    // phase3 @H0: B flat 11..14
    lrot4<1>(a0, a1, a2, a3, cBi[11], t);
    lrot4<2>(a0, a1, a2, a3, cBi[12], t);
    lrot4<4>(a0, a1, a2, a3, cBi[13], t);
    lrot4<8>(a0, a1, a2, a3, cBi[14], t);

    float4* gp2 = (float4*)(psi + ga);
    gp2[0] = make_float4(a0.x, a0.y, a1.x, a1.y);
    gp2[1] = make_float4(a2.x, a2.y, a3.x, a3.y);
}

extern "C" void kernel_launch(void* const* d_in, const int* in_sizes, int n_in,
                              void* d_out, int out_size, void* d_ws, size_t ws_size,
                              hipStream_t stream) {
    (void)in_sizes; (void)n_in; (void)out_size; (void)ws_size;
    const float* th = (const float*)d_in[0];   // (8,20)
    const float* ph = (const float*)d_in[1];   // (8,19)
    float2* psi = (float2*)d_ws;               // 2^20 complex64 = 8 MB
    float2* cw  = (float2*)((char*)d_ws + (8u << 20));              // coeffs
    float2* Dt  = (float2*)((char*)d_ws + (8u << 20) + 4096);       // 6x1536
    float* out = (float*)d_out;

    init_kernel      <<<512, 512, 0, stream>>>(psi, th, ph, cw, Dt);
    low_kernel<false><<<512, 512, 0, stream>>>(psi, cw + 1 * 20, cw + 2 * 20, Dt + 0 * 1536, nullptr);
    hi_kernel        <<<512, 512, 0, stream>>>(psi, cw + 2 * 20, cw + 3 * 20, Dt + 1 * 1536);
    low_kernel<false><<<512, 512, 0, stream>>>(psi, cw + 3 * 20, cw + 4 * 20, Dt + 2 * 1536, nullptr);
    hi_kernel        <<<512, 512, 0, stream>>>(psi, cw + 4 * 20, cw + 5 * 20, Dt + 3 * 1536);
    low_kernel<false><<<512, 512, 0, stream>>>(psi, cw + 5 * 20, cw + 6 * 20, Dt + 4 * 1536, nullptr);
    hi_kernel        <<<512, 512, 0, stream>>>(psi, cw + 6 * 20, cw + 7 * 20, Dt + 5 * 1536);
    low_kernel<true ><<<512, 512, 0, stream>>>(psi, cw + 7 * 20, cw + 7 * 20, nullptr, out);
}